// Round 8
// baseline (1032.735 us; speedup 1.0000x reference)
//
#include <hip/hip_runtime.h>
#include <hip/hip_bf16.h>
#include <cmath>

#define NL 16
#define TSIZE (1u << 19)
#define TMASK (TSIZE - 1u)
#define NBINS (1u << 18)     // 18-bit Morton key (6 bits/axis, res 64)

typedef __attribute__((ext_vector_type(8))) short bf16x8;     // 8 bf16 (4 VGPRs)
typedef __attribute__((ext_vector_type(4))) float f32x4;

struct LevelParams {
  float scale[NL];
  unsigned res[NL];
  unsigned dense_mask;
};

static __device__ __forceinline__ short f2bf(float f) {
  __hip_bfloat16 h = __float2bfloat16(f);
  return *reinterpret_cast<short*>(&h);
}
static __device__ __forceinline__ short lo16(unsigned u) { return (short)(u & 0xffffu); }
static __device__ __forceinline__ short hi16(unsigned u) { return (short)(u >> 16); }

// Morton spread (standard 10-bit spread3; inputs are 6-bit)
static __device__ __forceinline__ unsigned spread3(unsigned x) {
  x &= 0x3FFu;
  x = (x | (x << 16)) & 0x030000FFu;
  x = (x | (x << 8))  & 0x0300F00Fu;
  x = (x | (x << 4))  & 0x030C30C3u;
  x = (x | (x << 2))  & 0x09249249u;
  return x;
}
static __device__ __forceinline__ unsigned ray_key(float dx, float dy, float dz) {
  float X0 = dx * 0.49f + 0.49f;
  float X1 = dy * 0.49f + 0.49f;
  float X2 = dz * 0.49f + 0.49f;
  unsigned qx = (unsigned)(X0 * 64.0f); qx = qx > 63u ? 63u : qx;
  unsigned qy = (unsigned)(X1 * 64.0f); qy = qy > 63u ? 63u : qy;
  unsigned qz = (unsigned)(X2 * 64.0f); qz = qz > 63u ? 63u : qz;
  return spread3(qx) | (spread3(qy) << 1) | (spread3(qz) << 2);
}

// ============ Sort pipeline: counting sort on 18-bit Morton key ============
__global__ __launch_bounds__(256)
void hist_k(const float* __restrict__ dirs, unsigned* __restrict__ hist, int n) {
  int i = blockIdx.x * 256 + threadIdx.x;
  if (i >= n) return;
  unsigned key = ray_key(dirs[i * 3 + 0], dirs[i * 3 + 1], dirs[i * 3 + 2]);
  atomicAdd(&hist[key], 1u);
}

__global__ __launch_bounds__(1024)
void scan_k(unsigned* __restrict__ hist) {   // 1 block, 1024 thr, 256 bins each
  __shared__ unsigned sums[1024];
  int t = threadIdx.x;
  unsigned base = (unsigned)t * 256u;
  unsigned s = 0;
  for (int i = 0; i < 256; ++i) s += hist[base + i];
  sums[t] = s;
  __syncthreads();
  for (int off = 1; off < 1024; off <<= 1) {     // Hillis-Steele inclusive scan
    unsigned v = (t >= off) ? sums[t - off] : 0u;
    __syncthreads();
    sums[t] += v;
    __syncthreads();
  }
  unsigned run = (t > 0) ? sums[t - 1] : 0u;     // exclusive block offset
  for (int i = 0; i < 256; ++i) {
    unsigned c = hist[base + i];
    hist[base + i] = run;
    run += c;
  }
}

__global__ __launch_bounds__(256)
void scatter_k(const float* __restrict__ dirs, unsigned* __restrict__ hist,
               float* __restrict__ sdirs, unsigned* __restrict__ order, int n) {
  int i = blockIdx.x * 256 + threadIdx.x;
  if (i >= n) return;
  float dx = dirs[i * 3 + 0], dy = dirs[i * 3 + 1], dz = dirs[i * 3 + 2];
  unsigned key = ray_key(dx, dy, dz);
  unsigned pos = atomicAdd(&hist[key], 1u);
  sdirs[pos * 3 + 0] = dx;
  sdirs[pos * 3 + 1] = dy;
  sdirs[pos * 3 + 2] = dz;
  order[pos] = i;
}

// ============ Encode: 1 ray x 2 levels (l, l+8) per thread, XCD-pinned. =====
// Identical math to r7's verified encode_k5; input is SORTED dirs, so a
// wave's 64 rays share cells -> wave coalescer merges same-line lanes
// (attacks the ~0.5 unique-lines/cyc/CU TA cap directly).
__global__ __launch_bounds__(256)
void encode_k6(const float* __restrict__ dirs,
               const float* __restrict__ table,
               unsigned* __restrict__ ws,
               int n, LevelParams lp)
{
  int b = blockIdx.x;
  int l0 = b & 7;                     // XCD slot -> levels l0, l0+8
  int chunk = b >> 3;
  int ray = chunk * 256 + threadIdx.x;
  if (ray >= n) return;

  float X0 = dirs[ray * 3 + 0] * 0.49f + 0.49f;
  float X1 = dirs[ray * 3 + 1] * 0.49f + 0.49f;
  float X2 = dirs[ray * 3 + 2] * 0.49f + 0.49f;

  float wa0[2][3], wa1[2][3];
  bool dns[2];
  unsigned didx[2][8];
  unsigned par[2][4];
  const float2* tb[2];

  #pragma unroll
  for (int g = 0; g < 2; ++g) {
    int level = l0 + g * 8;
    float s = lp.scale[level];
    unsigned r = lp.res[level];
    dns[g] = (lp.dense_mask >> level) & 1u;

    float px = X0 * s + 0.5f, py = X1 * s + 0.5f, pz = X2 * s + 0.5f;
    float gx = floorf(px), gy = floorf(py), gz = floorf(pz);
    float fx = px - gx, fy = py - gy, fz = pz - gz;
    unsigned ix = (unsigned)gx, iy = (unsigned)gy, iz = (unsigned)gz;

    wa1[g][0] = fx * fx * (3.0f - 2.0f * fx);
    wa1[g][1] = fy * fy * (3.0f - 2.0f * fy);
    wa1[g][2] = fz * fz * (3.0f - 2.0f * fz);
    wa0[g][0] = 1.0f - wa1[g][0];
    wa0[g][1] = 1.0f - wa1[g][1];
    wa0[g][2] = 1.0f - wa1[g][2];

    if (dns[g]) {
      unsigned r2 = r * r;
      unsigned x0 = ix, x1 = ix + 1u;
      unsigned y0 = iy * r, y1 = y0 + r;
      unsigned z0 = iz * r2, z1 = z0 + r2;
      didx[g][0] = x0 + y0 + z0; didx[g][1] = x1 + y0 + z0;
      didx[g][2] = x0 + y1 + z0; didx[g][3] = x1 + y1 + z0;
      didx[g][4] = x0 + y0 + z1; didx[g][5] = x1 + y0 + z1;
      didx[g][6] = x0 + y1 + z1; didx[g][7] = x1 + y1 + z1;
    } else {
      unsigned y0 = iy * 2654435761u, y1 = y0 + 2654435761u;  // uint32 wrap == ref
      unsigned z0 = iz * 805459861u,  z1 = z0 + 805459861u;
      unsigned p0 = (ix ^ y0 ^ z0) & TMASK;
      unsigned p1 = (ix ^ y1 ^ z0) & TMASK;
      unsigned p2 = (ix ^ y0 ^ z1) & TMASK;
      unsigned p3 = (ix ^ y1 ^ z1) & TMASK;
      didx[g][0] = p0 >> 1; didx[g][1] = p1 >> 1;
      didx[g][2] = p2 >> 1; didx[g][3] = p3 >> 1;
      par[g][0] = p0 & 1u; par[g][1] = p1 & 1u;
      par[g][2] = p2 & 1u; par[g][3] = p3 & 1u;
    }
    tb[g] = (const float2*)table + (size_t)level * TSIZE;
  }

  float2 v[2][8];
  float4 f4[2][4];
  #pragma unroll
  for (int g = 0; g < 2; ++g) {
    if (dns[g]) {
      #pragma unroll
      for (int c = 0; c < 8; ++c) v[g][c] = tb[g][didx[g][c]];
    } else {
      const float4* t4p = (const float4*)tb[g];
      #pragma unroll
      for (int c = 0; c < 4; ++c) f4[g][c] = t4p[didx[g][c]];
    }
  }
  #pragma unroll
  for (int g = 0; g < 2; ++g) {
    if (!dns[g]) {
      #pragma unroll
      for (int c = 0; c < 4; ++c) {
        float2 even, odd;
        even.x = f4[g][c].x; even.y = f4[g][c].y;
        odd.x  = f4[g][c].z; odd.y  = f4[g][c].w;
        bool o = par[g][c] != 0;
        v[g][2 * c]     = o ? odd : even;
        v[g][2 * c + 1] = o ? even : odd;
      }
    }
  }

  #pragma unroll
  for (int g = 0; g < 2; ++g) {
    float wx0 = wa0[g][0], wx1 = wa1[g][0];
    float wy0 = wa0[g][1], wy1 = wa1[g][1];
    float wz0 = wa0[g][2], wz1 = wa1[g][2];
    float wy0z0 = wy0 * wz0, wy1z0 = wy1 * wz0, wy0z1 = wy0 * wz1, wy1z1 = wy1 * wz1;
    float w000 = wx0 * wy0z0, w100 = wx1 * wy0z0;
    float w010 = wx0 * wy1z0, w110 = wx1 * wy1z0;
    float w001 = wx0 * wy0z1, w101 = wx1 * wy0z1;
    float w011 = wx0 * wy1z1, w111 = wx1 * wy1z1;

    float a0 = w000 * v[g][0].x + w100 * v[g][1].x + w010 * v[g][2].x + w110 * v[g][3].x
             + w001 * v[g][4].x + w101 * v[g][5].x + w011 * v[g][6].x + w111 * v[g][7].x;
    float a1 = w000 * v[g][0].y + w100 * v[g][1].y + w010 * v[g][2].y + w110 * v[g][3].y
             + w001 * v[g][4].y + w101 * v[g][5].y + w011 * v[g][6].y + w111 * v[g][7].y;

    int level = l0 + g * 8;
    unsigned packed = ((unsigned)f2bf(a0) & 0xffffu) | (((unsigned)f2bf(a1) & 0xffffu) << 16);
    ws[(size_t)level * n + ray] = packed;
  }
}

// ============ MLP via bf16 MFMA; sorted space, scatter via order[] ==========
#define RPB 512
#define ROWS 72

__global__ __launch_bounds__(256)
void mlp_mfma4(const float* __restrict__ dirs,       // SORTED dirs
               const unsigned* __restrict__ ws,      // [16][n] bf16x2, sorted
               const unsigned* __restrict__ order,   // sorted pos -> orig ray
               const float* __restrict__ W1, const float* __restrict__ b1,
               const float* __restrict__ W2, const float* __restrict__ b2,
               const float* __restrict__ W3, const float* __restrict__ b3,
               float* __restrict__ out, int n)
{
  __shared__ short W1T[64 * ROWS];
  __shared__ short W2T[64 * ROWS];
  __shared__ short H1T[4][32 * ROWS];

  int tid = threadIdx.x;
  {
    int nn = tid >> 2;
    int kg = tid & 3;
    bf16x8 v1a, v1b, v2a, v2b;
    #pragma unroll
    for (int j = 0; j < 8; ++j) {
      int k0 = kg * 16 + j, k1 = kg * 16 + 8 + j;
      v1a[j] = (k0 < 32) ? f2bf(W1[(k0 + 3) * 64 + nn])
             : (k0 < 35) ? f2bf(W1[(k0 - 32) * 64 + nn]) : (short)0;
      v1b[j] = (k1 < 32) ? f2bf(W1[(k1 + 3) * 64 + nn])
             : (k1 < 35) ? f2bf(W1[(k1 - 32) * 64 + nn]) : (short)0;
      v2a[j] = f2bf(W2[k0 * 64 + nn]);
      v2b[j] = f2bf(W2[k1 * 64 + nn]);
    }
    int wo = nn * ROWS + kg * 16;
    *(bf16x8*)&W1T[wo]     = v1a;
    *(bf16x8*)&W1T[wo + 8] = v1b;
    *(bf16x8*)&W2T[wo]     = v2a;
    *(bf16x8*)&W2T[wo + 8] = v2b;
  }
  __syncthreads();

  int wave = tid >> 6, lane = tid & 63;
  int q = lane >> 4, nl = lane & 15;

  float b1v[4], b2v[4], w3v[4];
  #pragma unroll
  for (int t4 = 0; t4 < 4; ++t4) {
    b1v[t4] = b1[t4 * 16 + nl];
    b2v[t4] = b2[t4 * 16 + nl];
    w3v[t4] = W3[t4 * 16 + nl];
  }
  float b3s = b3[0];

  int blockBase = blockIdx.x * RPB;

  for (int batch = 0; batch < RPB / 128; ++batch) {
    int wbase = blockBase + batch * 128 + wave * 32;

    bf16x8 a0[2], a1[2];
    #pragma unroll
    for (int t = 0; t < 2; ++t) {
      int rr = wbase + t * 16 + nl;
      int rc = rr < n ? rr : (n - 1);
      unsigned u0 = ws[(size_t)(q * 4 + 0) * n + rc];
      unsigned u1 = ws[(size_t)(q * 4 + 1) * n + rc];
      unsigned u2 = ws[(size_t)(q * 4 + 2) * n + rc];
      unsigned u3 = ws[(size_t)(q * 4 + 3) * n + rc];
      a0[t][0] = lo16(u0); a0[t][1] = hi16(u0); a0[t][2] = lo16(u1); a0[t][3] = hi16(u1);
      a0[t][4] = lo16(u2); a0[t][5] = hi16(u2); a0[t][6] = lo16(u3); a0[t][7] = hi16(u3);
      a1[t][0] = 0; a1[t][1] = 0; a1[t][2] = 0; a1[t][3] = 0;
      a1[t][4] = 0; a1[t][5] = 0; a1[t][6] = 0; a1[t][7] = 0;
      if (q == 0) {
        a1[t][0] = f2bf(dirs[rc * 3 + 0]);
        a1[t][1] = f2bf(dirs[rc * 3 + 1]);
        a1[t][2] = f2bf(dirs[rc * 3 + 2]);
      }
    }

    f32x4 acc[2][4];
    #pragma unroll
    for (int t4 = 0; t4 < 4; ++t4) {
      int brow = (t4 * 16 + nl) * ROWS;
      bf16x8 bt0 = *(const bf16x8*)&W1T[brow + q * 8];
      bf16x8 bt1 = *(const bf16x8*)&W1T[brow + 32 + q * 8];
      #pragma unroll
      for (int t = 0; t < 2; ++t) {
        f32x4 z = {0.f, 0.f, 0.f, 0.f};
        z = __builtin_amdgcn_mfma_f32_16x16x32_bf16(a0[t], bt0, z, 0, 0, 0);
        z = __builtin_amdgcn_mfma_f32_16x16x32_bf16(a1[t], bt1, z, 0, 0, 0);
        acc[t][t4] = z;
      }
    }
    #pragma unroll
    for (int t = 0; t < 2; ++t)
      #pragma unroll
      for (int t4 = 0; t4 < 4; ++t4)
        #pragma unroll
        for (int i = 0; i < 4; ++i) {
          float v = fmaxf(acc[t][t4][i] + b1v[t4], 0.0f);
          H1T[wave][(t * 16 + q * 4 + i) * ROWS + t4 * 16 + nl] = f2bf(v);
        }
    __syncthreads();   // H1 visible + compiler fence (round-3 lesson)

    #pragma unroll
    for (int t4 = 0; t4 < 4; ++t4) {
      int brow = (t4 * 16 + nl) * ROWS;
      bf16x8 bt0 = *(const bf16x8*)&W2T[brow + q * 8];
      bf16x8 bt1 = *(const bf16x8*)&W2T[brow + 32 + q * 8];
      #pragma unroll
      for (int t = 0; t < 2; ++t) {
        bf16x8 h0 = *(const bf16x8*)&H1T[wave][(t * 16 + nl) * ROWS + q * 8];
        bf16x8 h1f = *(const bf16x8*)&H1T[wave][(t * 16 + nl) * ROWS + 32 + q * 8];
        f32x4 z = {0.f, 0.f, 0.f, 0.f};
        z = __builtin_amdgcn_mfma_f32_16x16x32_bf16(h0, bt0, z, 0, 0, 0);
        z = __builtin_amdgcn_mfma_f32_16x16x32_bf16(h1f, bt1, z, 0, 0, 0);
        acc[t][t4] = z;
      }
    }

    #pragma unroll
    for (int t = 0; t < 2; ++t) {
      float part[4] = {0.f, 0.f, 0.f, 0.f};
      #pragma unroll
      for (int t4 = 0; t4 < 4; ++t4)
        #pragma unroll
        for (int i = 0; i < 4; ++i) {
          float v = fmaxf(acc[t][t4][i] + b2v[t4], 0.0f);
          part[i] = fmaf(v, w3v[t4], part[i]);
        }
      #pragma unroll
      for (int s = 1; s < 16; s <<= 1) {
        #pragma unroll
        for (int i = 0; i < 4; ++i) part[i] += __shfl_xor(part[i], s, 64);
      }
      if (nl == 0) {
        int orow = wbase + t * 16 + q * 4;
        #pragma unroll
        for (int i = 0; i < 4; ++i) {
          if (orow + i < n) {
            float v = part[i] + b3s + 1.0f;
            out[order[orow + i]] = fmaxf(v, 0.0f) + log1pf(expf(-fabsf(v)));
          }
        }
      }
    }
    __syncthreads();   // WAR fence for next batch
  }
}

// ============ Fallback path A (r7, ws >= 128MiB only): unsorted =============
__global__ __launch_bounds__(256)
void mlp_mfma3(const float* __restrict__ dirs,
               const unsigned* __restrict__ ws,
               const float* __restrict__ W1, const float* __restrict__ b1,
               const float* __restrict__ W2, const float* __restrict__ b2,
               const float* __restrict__ W3, const float* __restrict__ b3,
               float* __restrict__ out, int n)
{
  __shared__ short W1T[64 * ROWS];
  __shared__ short W2T[64 * ROWS];
  __shared__ short H1T[4][32 * ROWS];

  int tid = threadIdx.x;
  {
    int nn = tid >> 2;
    int kg = tid & 3;
    bf16x8 v1a, v1b, v2a, v2b;
    #pragma unroll
    for (int j = 0; j < 8; ++j) {
      int k0 = kg * 16 + j, k1 = kg * 16 + 8 + j;
      v1a[j] = (k0 < 32) ? f2bf(W1[(k0 + 3) * 64 + nn])
             : (k0 < 35) ? f2bf(W1[(k0 - 32) * 64 + nn]) : (short)0;
      v1b[j] = (k1 < 32) ? f2bf(W1[(k1 + 3) * 64 + nn])
             : (k1 < 35) ? f2bf(W1[(k1 - 32) * 64 + nn]) : (short)0;
      v2a[j] = f2bf(W2[k0 * 64 + nn]);
      v2b[j] = f2bf(W2[k1 * 64 + nn]);
    }
    int wo = nn * ROWS + kg * 16;
    *(bf16x8*)&W1T[wo]     = v1a;
    *(bf16x8*)&W1T[wo + 8] = v1b;
    *(bf16x8*)&W2T[wo]     = v2a;
    *(bf16x8*)&W2T[wo + 8] = v2b;
  }
  __syncthreads();

  int wave = tid >> 6, lane = tid & 63;
  int q = lane >> 4, nl = lane & 15;

  float b1v[4], b2v[4], w3v[4];
  #pragma unroll
  for (int t4 = 0; t4 < 4; ++t4) {
    b1v[t4] = b1[t4 * 16 + nl];
    b2v[t4] = b2[t4 * 16 + nl];
    w3v[t4] = W3[t4 * 16 + nl];
  }
  float b3s = b3[0];

  int blockBase = blockIdx.x * RPB;

  for (int batch = 0; batch < RPB / 128; ++batch) {
    int wbase = blockBase + batch * 128 + wave * 32;
    bf16x8 a0[2], a1[2];
    #pragma unroll
    for (int t = 0; t < 2; ++t) {
      int rr = wbase + t * 16 + nl;
      int rc = rr < n ? rr : (n - 1);
      unsigned u0 = ws[(size_t)(q * 4 + 0) * n + rc];
      unsigned u1 = ws[(size_t)(q * 4 + 1) * n + rc];
      unsigned u2 = ws[(size_t)(q * 4 + 2) * n + rc];
      unsigned u3 = ws[(size_t)(q * 4 + 3) * n + rc];
      a0[t][0] = lo16(u0); a0[t][1] = hi16(u0); a0[t][2] = lo16(u1); a0[t][3] = hi16(u1);
      a0[t][4] = lo16(u2); a0[t][5] = hi16(u2); a0[t][6] = lo16(u3); a0[t][7] = hi16(u3);
      a1[t][0] = 0; a1[t][1] = 0; a1[t][2] = 0; a1[t][3] = 0;
      a1[t][4] = 0; a1[t][5] = 0; a1[t][6] = 0; a1[t][7] = 0;
      if (q == 0) {
        a1[t][0] = f2bf(dirs[rc * 3 + 0]);
        a1[t][1] = f2bf(dirs[rc * 3 + 1]);
        a1[t][2] = f2bf(dirs[rc * 3 + 2]);
      }
    }

    f32x4 acc[2][4];
    #pragma unroll
    for (int t4 = 0; t4 < 4; ++t4) {
      int brow = (t4 * 16 + nl) * ROWS;
      bf16x8 bt0 = *(const bf16x8*)&W1T[brow + q * 8];
      bf16x8 bt1 = *(const bf16x8*)&W1T[brow + 32 + q * 8];
      #pragma unroll
      for (int t = 0; t < 2; ++t) {
        f32x4 z = {0.f, 0.f, 0.f, 0.f};
        z = __builtin_amdgcn_mfma_f32_16x16x32_bf16(a0[t], bt0, z, 0, 0, 0);
        z = __builtin_amdgcn_mfma_f32_16x16x32_bf16(a1[t], bt1, z, 0, 0, 0);
        acc[t][t4] = z;
      }
    }
    #pragma unroll
    for (int t = 0; t < 2; ++t)
      #pragma unroll
      for (int t4 = 0; t4 < 4; ++t4)
        #pragma unroll
        for (int i = 0; i < 4; ++i) {
          float v = fmaxf(acc[t][t4][i] + b1v[t4], 0.0f);
          H1T[wave][(t * 16 + q * 4 + i) * ROWS + t4 * 16 + nl] = f2bf(v);
        }
    __syncthreads();

    #pragma unroll
    for (int t4 = 0; t4 < 4; ++t4) {
      int brow = (t4 * 16 + nl) * ROWS;
      bf16x8 bt0 = *(const bf16x8*)&W2T[brow + q * 8];
      bf16x8 bt1 = *(const bf16x8*)&W2T[brow + 32 + q * 8];
      #pragma unroll
      for (int t = 0; t < 2; ++t) {
        bf16x8 h0 = *(const bf16x8*)&H1T[wave][(t * 16 + nl) * ROWS + q * 8];
        bf16x8 h1f = *(const bf16x8*)&H1T[wave][(t * 16 + nl) * ROWS + 32 + q * 8];
        f32x4 z = {0.f, 0.f, 0.f, 0.f};
        z = __builtin_amdgcn_mfma_f32_16x16x32_bf16(h0, bt0, z, 0, 0, 0);
        z = __builtin_amdgcn_mfma_f32_16x16x32_bf16(h1f, bt1, z, 0, 0, 0);
        acc[t][t4] = z;
      }
    }

    #pragma unroll
    for (int t = 0; t < 2; ++t) {
      float part[4] = {0.f, 0.f, 0.f, 0.f};
      #pragma unroll
      for (int t4 = 0; t4 < 4; ++t4)
        #pragma unroll
        for (int i = 0; i < 4; ++i) {
          float v = fmaxf(acc[t][t4][i] + b2v[t4], 0.0f);
          part[i] = fmaf(v, w3v[t4], part[i]);
        }
      #pragma unroll
      for (int s = 1; s < 16; s <<= 1) {
        #pragma unroll
        for (int i = 0; i < 4; ++i) part[i] += __shfl_xor(part[i], s, 64);
      }
      if (nl == 0) {
        int orow = wbase + t * 16 + q * 4;
        float ov[4];
        #pragma unroll
        for (int i = 0; i < 4; ++i) {
          float v = part[i] + b3s + 1.0f;
          ov[i] = fmaxf(v, 0.0f) + log1pf(expf(-fabsf(v)));
        }
        if (orow + 3 < n) {
          float4 o4; o4.x = ov[0]; o4.y = ov[1]; o4.z = ov[2]; o4.w = ov[3];
          *(float4*)&out[orow] = o4;
        } else {
          for (int i = 0; i < 4; ++i) if (orow + i < n) out[orow + i] = ov[i];
        }
      }
    }
    __syncthreads();
  }
}

// ============ Fallback path B: round-1 fused kernel (tiny ws) ===============
__global__ __launch_bounds__(256)
void sdf_fused(const float* __restrict__ dirs,
               const float* __restrict__ table,
               const float* __restrict__ W1, const float* __restrict__ b1,
               const float* __restrict__ W2, const float* __restrict__ b2,
               const float* __restrict__ W3, const float* __restrict__ b3,
               float* __restrict__ out, int n, LevelParams lp)
{
  int gid = blockIdx.x * 256 + threadIdx.x;
  if (gid >= n) return;
  float dx = dirs[gid * 3 + 0], dy = dirs[gid * 3 + 1], dz = dirs[gid * 3 + 2];
  float xx = dx * 0.49f + 0.49f, xy = dy * 0.49f + 0.49f, xz = dz * 0.49f + 0.49f;
  float h[35];
  h[0] = dx; h[1] = dy; h[2] = dz;
  #pragma unroll
  for (int l = 0; l < NL; ++l) {
    float s = lp.scale[l];
    float px = xx * s + 0.5f, py = xy * s + 0.5f, pz = xz * s + 0.5f;
    float gx = floorf(px), gy = floorf(py), gz = floorf(pz);
    float fx = px - gx, fy = py - gy, fz = pz - gz;
    unsigned ix = (unsigned)gx, iy = (unsigned)gy, iz = (unsigned)gz;
    float wx1 = fx * fx * (3.0f - 2.0f * fx);
    float wy1 = fy * fy * (3.0f - 2.0f * fy);
    float wz1 = fz * fz * (3.0f - 2.0f * fz);
    float wx0 = 1.0f - wx1, wy0 = 1.0f - wy1, wz0 = 1.0f - wz1;
    unsigned i000, i100, i010, i110, i001, i101, i011, i111;
    if ((lp.dense_mask >> l) & 1u) {
      unsigned r = lp.res[l], r2 = r * r;
      unsigned x0 = ix, x1 = ix + 1u, y0 = iy * r, y1 = y0 + r, z0 = iz * r2, z1 = z0 + r2;
      i000 = x0 + y0 + z0; i100 = x1 + y0 + z0; i010 = x0 + y1 + z0; i110 = x1 + y1 + z0;
      i001 = x0 + y0 + z1; i101 = x1 + y0 + z1; i011 = x0 + y1 + z1; i111 = x1 + y1 + z1;
    } else {
      unsigned x0 = ix, x1 = ix + 1u;
      unsigned y0 = iy * 2654435761u, y1 = y0 + 2654435761u;
      unsigned z0 = iz * 805459861u,  z1 = z0 + 805459861u;
      i000 = (x0 ^ y0 ^ z0) & TMASK; i100 = (x1 ^ y0 ^ z0) & TMASK;
      i010 = (x0 ^ y1 ^ z0) & TMASK; i110 = (x1 ^ y1 ^ z0) & TMASK;
      i001 = (x0 ^ y0 ^ z1) & TMASK; i101 = (x1 ^ y0 ^ z1) & TMASK;
      i011 = (x0 ^ y1 ^ z1) & TMASK; i111 = (x1 ^ y1 ^ z1) & TMASK;
    }
    const float2* t = (const float2*)table + (size_t)l * TSIZE;
    float2 f000 = t[i000], f100 = t[i100], f010 = t[i010], f110 = t[i110];
    float2 f001 = t[i001], f101 = t[i101], f011 = t[i011], f111 = t[i111];
    float wy0z0 = wy0 * wz0, wy1z0 = wy1 * wz0, wy0z1 = wy0 * wz1, wy1z1 = wy1 * wz1;
    float w000 = wx0 * wy0z0, w100 = wx1 * wy0z0, w010 = wx0 * wy1z0, w110 = wx1 * wy1z0;
    float w001 = wx0 * wy0z1, w101 = wx1 * wy0z1, w011 = wx0 * wy1z1, w111 = wx1 * wy1z1;
    h[3 + 2 * l] = w000 * f000.x + w100 * f100.x + w010 * f010.x + w110 * f110.x
                 + w001 * f001.x + w101 * f101.x + w011 * f011.x + w111 * f111.x;
    h[4 + 2 * l] = w000 * f000.y + w100 * f100.y + w010 * f010.y + w110 * f110.y
                 + w001 * f001.y + w101 * f101.y + w011 * f011.y + w111 * f111.y;
  }
  float h1[64];
  #pragma unroll
  for (int j = 0; j < 64; ++j) {
    float acc = b1[j];
    #pragma unroll
    for (int i = 0; i < 35; ++i) acc = fmaf(h[i], W1[i * 64 + j], acc);
    h1[j] = fmaxf(acc, 0.0f);
  }
  float h2[64];
  #pragma unroll
  for (int j = 0; j < 64; ++j) {
    float acc = b2[j];
    #pragma unroll
    for (int i = 0; i < 64; ++i) acc = fmaf(h1[i], W2[i * 64 + j], acc);
    h2[j] = fmaxf(acc, 0.0f);
  }
  float o = b3[0];
  #pragma unroll
  for (int i = 0; i < 64; ++i) o = fmaf(h2[i], W3[i], o);
  float v = o + 1.0f;
  out[gid] = fmaxf(v, 0.0f) + log1pf(expf(-fabsf(v)));
}

extern "C" void kernel_launch(void* const* d_in, const int* in_sizes, int n_in,
                              void* d_out, int out_size, void* d_ws, size_t ws_size,
                              hipStream_t stream) {
  const float* dirs  = (const float*)d_in[0];
  const float* table = (const float*)d_in[1];
  const float* W1 = (const float*)d_in[2];
  const float* b1 = (const float*)d_in[3];
  const float* W2 = (const float*)d_in[4];
  const float* b2 = (const float*)d_in[5];
  const float* W3 = (const float*)d_in[6];
  const float* b3 = (const float*)d_in[7];
  float* out = (float*)d_out;
  int n = in_sizes[0] / 3;

  LevelParams lp;
  double pls = std::exp(std::log(2048.0 / 16.0) / 15.0);
  unsigned dm = 0;
  for (int l = 0; l < NL; ++l) {
    double scale = 16.0 * std::pow(pls, (double)l) - 1.0;
    lp.scale[l] = (float)scale;
    long long res = (long long)std::ceil(scale) + 1;
    lp.res[l] = (unsigned)res;
    if (res * res * res <= (long long)TSIZE) dm |= (1u << l);
  }
  lp.dense_mask = dm;

  size_t feat_bytes  = (size_t)n * NL * 4;         // 128 MiB at n=2M
  size_t sdirs_bytes = (size_t)n * 12;
  size_t order_bytes = (size_t)n * 4;
  size_t hist_bytes  = (size_t)NBINS * 4;
  size_t sorted_need = feat_bytes + sdirs_bytes + order_bytes + hist_bytes;

  int blocks256 = (n + 255) / 256;
  int mlp_blocks = (n + RPB - 1) / RPB;

  if (ws_size >= sorted_need) {
    char* base = (char*)d_ws;
    unsigned* feats = (unsigned*)base;
    float*    sdirs = (float*)(base + feat_bytes);
    unsigned* order = (unsigned*)(base + feat_bytes + sdirs_bytes);
    unsigned* hist  = (unsigned*)(base + feat_bytes + sdirs_bytes + order_bytes);

    hipMemsetAsync(hist, 0, hist_bytes, stream);
    hipLaunchKernelGGL(hist_k, dim3(blocks256), dim3(256), 0, stream, dirs, hist, n);
    hipLaunchKernelGGL(scan_k, dim3(1), dim3(1024), 0, stream, hist);
    hipLaunchKernelGGL(scatter_k, dim3(blocks256), dim3(256), 0, stream,
                       dirs, hist, sdirs, order, n);
    hipLaunchKernelGGL(encode_k6, dim3(8 * blocks256), dim3(256), 0, stream,
                       sdirs, table, feats, n, lp);
    hipLaunchKernelGGL(mlp_mfma4, dim3(mlp_blocks), dim3(256), 0, stream,
                       sdirs, feats, order, W1, b1, W2, b2, W3, b3, out, n);
  } else if (ws_size >= feat_bytes) {
    // r7 path (verified, 951 us)
    unsigned* feats = (unsigned*)d_ws;
    hipLaunchKernelGGL(encode_k6, dim3(8 * blocks256), dim3(256), 0, stream,
                       dirs, table, feats, n, lp);
    hipLaunchKernelGGL(mlp_mfma3, dim3(mlp_blocks), dim3(256), 0, stream,
                       dirs, feats, W1, b1, W2, b2, W3, b3, out, n);
  } else {
    hipLaunchKernelGGL(sdf_fused, dim3(blocks256), dim3(256), 0, stream,
                       dirs, table, W1, b1, W2, b2, W3, b3, out, n, lp);
  }
}

// Round 9
// 935.647 us; speedup vs baseline: 1.1038x; 1.1038x over previous
//
#include <hip/hip_runtime.h>
#include <hip/hip_bf16.h>
#include <cmath>

#define NL 16
#define TSIZE (1u << 19)
#define TMASK (TSIZE - 1u)
#define NBINS (1u << 18)     // 18-bit Morton key (6 bits/axis, res 64)

typedef __attribute__((ext_vector_type(8))) short bf16x8;     // 8 bf16 (4 VGPRs)
typedef __attribute__((ext_vector_type(4))) float f32x4;

struct LevelParams {
  float scale[NL];
  unsigned res[NL];
  unsigned dense_mask;
};

static __device__ __forceinline__ short f2bf(float f) {
  __hip_bfloat16 h = __float2bfloat16(f);
  return *reinterpret_cast<short*>(&h);
}
static __device__ __forceinline__ short lo16(unsigned u) { return (short)(u & 0xffffu); }
static __device__ __forceinline__ short hi16(unsigned u) { return (short)(u >> 16); }

// Morton spread (standard 10-bit spread3; inputs are 6-bit)
static __device__ __forceinline__ unsigned spread3(unsigned x) {
  x &= 0x3FFu;
  x = (x | (x << 16)) & 0x030000FFu;
  x = (x | (x << 8))  & 0x0300F00Fu;
  x = (x | (x << 4))  & 0x030C30C3u;
  x = (x | (x << 2))  & 0x09249249u;
  return x;
}
static __device__ __forceinline__ unsigned ray_key(float dx, float dy, float dz) {
  float X0 = dx * 0.49f + 0.49f;
  float X1 = dy * 0.49f + 0.49f;
  float X2 = dz * 0.49f + 0.49f;
  unsigned qx = (unsigned)(X0 * 64.0f); qx = qx > 63u ? 63u : qx;
  unsigned qy = (unsigned)(X1 * 64.0f); qy = qy > 63u ? 63u : qy;
  unsigned qz = (unsigned)(X2 * 64.0f); qz = qz > 63u ? 63u : qz;
  return spread3(qx) | (spread3(qy) << 1) | (spread3(qz) << 2);
}

// ============ Sort pipeline: counting sort on 18-bit Morton key ============
__global__ __launch_bounds__(256)
void hist_k(const float* __restrict__ dirs, unsigned* __restrict__ hist, int n) {
  int i = blockIdx.x * 256 + threadIdx.x;
  if (i >= n) return;
  unsigned key = ray_key(dirs[i * 3 + 0], dirs[i * 3 + 1], dirs[i * 3 + 2]);
  atomicAdd(&hist[key], 1u);
}

// Hierarchical scan (r8 lesson: single-block scan over 256K bins was ~400 us
// serialized on one CU). 256 blocks x 256 thr x 4 bins = 256K.
__global__ __launch_bounds__(256)
void scanA_k(unsigned* __restrict__ hist, unsigned* __restrict__ blockSums) {
  __shared__ unsigned sums[256];
  int bid = blockIdx.x, t = threadIdx.x;
  unsigned base = (unsigned)bid * 1024u + (unsigned)t * 4u;
  uint4 c = *(uint4*)&hist[base];
  unsigned s = c.x + c.y + c.z + c.w;
  sums[t] = s;
  __syncthreads();
  for (int off = 1; off < 256; off <<= 1) {   // Hillis-Steele inclusive
    unsigned v = (t >= off) ? sums[t - off] : 0u;
    __syncthreads();
    sums[t] += v;
    __syncthreads();
  }
  unsigned excl = sums[t] - s;                // exclusive prefix within block
  uint4 o;
  o.x = excl;
  o.y = excl + c.x;
  o.z = excl + c.x + c.y;
  o.w = excl + c.x + c.y + c.z;
  *(uint4*)&hist[base] = o;
  if (t == 255) blockSums[bid] = sums[255];   // block total
}

__global__ __launch_bounds__(256)
void scanB_k(unsigned* __restrict__ blockSums) {   // 1 block, 256 entries
  __shared__ unsigned sums[256];
  int t = threadIdx.x;
  unsigned s = blockSums[t];
  sums[t] = s;
  __syncthreads();
  for (int off = 1; off < 256; off <<= 1) {
    unsigned v = (t >= off) ? sums[t - off] : 0u;
    __syncthreads();
    sums[t] += v;
    __syncthreads();
  }
  blockSums[t] = sums[t] - s;                 // exclusive
}

__global__ __launch_bounds__(256)
void scanC_k(unsigned* __restrict__ hist, const unsigned* __restrict__ blockSums) {
  int bid = blockIdx.x, t = threadIdx.x;
  unsigned off = blockSums[bid];
  unsigned base = (unsigned)bid * 1024u + (unsigned)t * 4u;
  uint4 c = *(uint4*)&hist[base];
  c.x += off; c.y += off; c.z += off; c.w += off;
  *(uint4*)&hist[base] = c;
}

__global__ __launch_bounds__(256)
void scatter_k(const float* __restrict__ dirs, unsigned* __restrict__ hist,
               float* __restrict__ sdirs, unsigned* __restrict__ order, int n) {
  int i = blockIdx.x * 256 + threadIdx.x;
  if (i >= n) return;
  float dx = dirs[i * 3 + 0], dy = dirs[i * 3 + 1], dz = dirs[i * 3 + 2];
  unsigned key = ray_key(dx, dy, dz);
  unsigned pos = atomicAdd(&hist[key], 1u);
  sdirs[pos * 3 + 0] = dx;
  sdirs[pos * 3 + 1] = dy;
  sdirs[pos * 3 + 2] = dz;
  order[pos] = i;
}

// ============ Encode: 1 ray x 2 levels (l, l+8) per thread, XCD-pinned. =====
// Sorted input -> wave coalescer dedups same-line lanes (r8 verified:
// encode 700 -> 333 us, FETCH 1.26 GB -> 0.42 GB).
__global__ __launch_bounds__(256)
void encode_k6(const float* __restrict__ dirs,
               const float* __restrict__ table,
               unsigned* __restrict__ ws,
               int n, LevelParams lp)
{
  int b = blockIdx.x;
  int l0 = b & 7;                     // XCD slot -> levels l0, l0+8
  int chunk = b >> 3;
  int ray = chunk * 256 + threadIdx.x;
  if (ray >= n) return;

  float X0 = dirs[ray * 3 + 0] * 0.49f + 0.49f;
  float X1 = dirs[ray * 3 + 1] * 0.49f + 0.49f;
  float X2 = dirs[ray * 3 + 2] * 0.49f + 0.49f;

  float wa0[2][3], wa1[2][3];
  bool dns[2];
  unsigned didx[2][8];
  unsigned par[2][4];
  const float2* tb[2];

  #pragma unroll
  for (int g = 0; g < 2; ++g) {
    int level = l0 + g * 8;
    float s = lp.scale[level];
    unsigned r = lp.res[level];
    dns[g] = (lp.dense_mask >> level) & 1u;

    float px = X0 * s + 0.5f, py = X1 * s + 0.5f, pz = X2 * s + 0.5f;
    float gx = floorf(px), gy = floorf(py), gz = floorf(pz);
    float fx = px - gx, fy = py - gy, fz = pz - gz;
    unsigned ix = (unsigned)gx, iy = (unsigned)gy, iz = (unsigned)gz;

    wa1[g][0] = fx * fx * (3.0f - 2.0f * fx);
    wa1[g][1] = fy * fy * (3.0f - 2.0f * fy);
    wa1[g][2] = fz * fz * (3.0f - 2.0f * fz);
    wa0[g][0] = 1.0f - wa1[g][0];
    wa0[g][1] = 1.0f - wa1[g][1];
    wa0[g][2] = 1.0f - wa1[g][2];

    if (dns[g]) {
      unsigned r2 = r * r;
      unsigned x0 = ix, x1 = ix + 1u;
      unsigned y0 = iy * r, y1 = y0 + r;
      unsigned z0 = iz * r2, z1 = z0 + r2;
      didx[g][0] = x0 + y0 + z0; didx[g][1] = x1 + y0 + z0;
      didx[g][2] = x0 + y1 + z0; didx[g][3] = x1 + y1 + z0;
      didx[g][4] = x0 + y0 + z1; didx[g][5] = x1 + y0 + z1;
      didx[g][6] = x0 + y1 + z1; didx[g][7] = x1 + y1 + z1;
    } else {
      unsigned y0 = iy * 2654435761u, y1 = y0 + 2654435761u;  // uint32 wrap == ref
      unsigned z0 = iz * 805459861u,  z1 = z0 + 805459861u;
      unsigned p0 = (ix ^ y0 ^ z0) & TMASK;
      unsigned p1 = (ix ^ y1 ^ z0) & TMASK;
      unsigned p2 = (ix ^ y0 ^ z1) & TMASK;
      unsigned p3 = (ix ^ y1 ^ z1) & TMASK;
      didx[g][0] = p0 >> 1; didx[g][1] = p1 >> 1;
      didx[g][2] = p2 >> 1; didx[g][3] = p3 >> 1;
      par[g][0] = p0 & 1u; par[g][1] = p1 & 1u;
      par[g][2] = p2 & 1u; par[g][3] = p3 & 1u;
    }
    tb[g] = (const float2*)table + (size_t)level * TSIZE;
  }

  float2 v[2][8];
  float4 f4[2][4];
  #pragma unroll
  for (int g = 0; g < 2; ++g) {
    if (dns[g]) {
      #pragma unroll
      for (int c = 0; c < 8; ++c) v[g][c] = tb[g][didx[g][c]];
    } else {
      const float4* t4p = (const float4*)tb[g];
      #pragma unroll
      for (int c = 0; c < 4; ++c) f4[g][c] = t4p[didx[g][c]];
    }
  }
  #pragma unroll
  for (int g = 0; g < 2; ++g) {
    if (!dns[g]) {
      #pragma unroll
      for (int c = 0; c < 4; ++c) {
        float2 even, odd;
        even.x = f4[g][c].x; even.y = f4[g][c].y;
        odd.x  = f4[g][c].z; odd.y  = f4[g][c].w;
        bool o = par[g][c] != 0;
        v[g][2 * c]     = o ? odd : even;
        v[g][2 * c + 1] = o ? even : odd;
      }
    }
  }

  #pragma unroll
  for (int g = 0; g < 2; ++g) {
    float wx0 = wa0[g][0], wx1 = wa1[g][0];
    float wy0 = wa0[g][1], wy1 = wa1[g][1];
    float wz0 = wa0[g][2], wz1 = wa1[g][2];
    float wy0z0 = wy0 * wz0, wy1z0 = wy1 * wz0, wy0z1 = wy0 * wz1, wy1z1 = wy1 * wz1;
    float w000 = wx0 * wy0z0, w100 = wx1 * wy0z0;
    float w010 = wx0 * wy1z0, w110 = wx1 * wy1z0;
    float w001 = wx0 * wy0z1, w101 = wx1 * wy0z1;
    float w011 = wx0 * wy1z1, w111 = wx1 * wy1z1;

    float a0 = w000 * v[g][0].x + w100 * v[g][1].x + w010 * v[g][2].x + w110 * v[g][3].x
             + w001 * v[g][4].x + w101 * v[g][5].x + w011 * v[g][6].x + w111 * v[g][7].x;
    float a1 = w000 * v[g][0].y + w100 * v[g][1].y + w010 * v[g][2].y + w110 * v[g][3].y
             + w001 * v[g][4].y + w101 * v[g][5].y + w011 * v[g][6].y + w111 * v[g][7].y;

    int level = l0 + g * 8;
    unsigned packed = ((unsigned)f2bf(a0) & 0xffffu) | (((unsigned)f2bf(a1) & 0xffffu) << 16);
    ws[(size_t)level * n + ray] = packed;
  }
}

// ============ MLP via bf16 MFMA; sorted space, scatter via order[] ==========
#define RPB 512
#define ROWS 72

__global__ __launch_bounds__(256)
void mlp_mfma4(const float* __restrict__ dirs,       // SORTED dirs
               const unsigned* __restrict__ ws,      // [16][n] bf16x2, sorted
               const unsigned* __restrict__ order,   // sorted pos -> orig ray
               const float* __restrict__ W1, const float* __restrict__ b1,
               const float* __restrict__ W2, const float* __restrict__ b2,
               const float* __restrict__ W3, const float* __restrict__ b3,
               float* __restrict__ out, int n)
{
  __shared__ short W1T[64 * ROWS];
  __shared__ short W2T[64 * ROWS];
  __shared__ short H1T[4][32 * ROWS];

  int tid = threadIdx.x;
  {
    int nn = tid >> 2;
    int kg = tid & 3;
    bf16x8 v1a, v1b, v2a, v2b;
    #pragma unroll
    for (int j = 0; j < 8; ++j) {
      int k0 = kg * 16 + j, k1 = kg * 16 + 8 + j;
      v1a[j] = (k0 < 32) ? f2bf(W1[(k0 + 3) * 64 + nn])
             : (k0 < 35) ? f2bf(W1[(k0 - 32) * 64 + nn]) : (short)0;
      v1b[j] = (k1 < 32) ? f2bf(W1[(k1 + 3) * 64 + nn])
             : (k1 < 35) ? f2bf(W1[(k1 - 32) * 64 + nn]) : (short)0;
      v2a[j] = f2bf(W2[k0 * 64 + nn]);
      v2b[j] = f2bf(W2[k1 * 64 + nn]);
    }
    int wo = nn * ROWS + kg * 16;
    *(bf16x8*)&W1T[wo]     = v1a;
    *(bf16x8*)&W1T[wo + 8] = v1b;
    *(bf16x8*)&W2T[wo]     = v2a;
    *(bf16x8*)&W2T[wo + 8] = v2b;
  }
  __syncthreads();

  int wave = tid >> 6, lane = tid & 63;
  int q = lane >> 4, nl = lane & 15;

  float b1v[4], b2v[4], w3v[4];
  #pragma unroll
  for (int t4 = 0; t4 < 4; ++t4) {
    b1v[t4] = b1[t4 * 16 + nl];
    b2v[t4] = b2[t4 * 16 + nl];
    w3v[t4] = W3[t4 * 16 + nl];
  }
  float b3s = b3[0];

  int blockBase = blockIdx.x * RPB;

  for (int batch = 0; batch < RPB / 128; ++batch) {
    int wbase = blockBase + batch * 128 + wave * 32;

    bf16x8 a0[2], a1[2];
    #pragma unroll
    for (int t = 0; t < 2; ++t) {
      int rr = wbase + t * 16 + nl;
      int rc = rr < n ? rr : (n - 1);
      unsigned u0 = ws[(size_t)(q * 4 + 0) * n + rc];
      unsigned u1 = ws[(size_t)(q * 4 + 1) * n + rc];
      unsigned u2 = ws[(size_t)(q * 4 + 2) * n + rc];
      unsigned u3 = ws[(size_t)(q * 4 + 3) * n + rc];
      a0[t][0] = lo16(u0); a0[t][1] = hi16(u0); a0[t][2] = lo16(u1); a0[t][3] = hi16(u1);
      a0[t][4] = lo16(u2); a0[t][5] = hi16(u2); a0[t][6] = lo16(u3); a0[t][7] = hi16(u3);
      a1[t][0] = 0; a1[t][1] = 0; a1[t][2] = 0; a1[t][3] = 0;
      a1[t][4] = 0; a1[t][5] = 0; a1[t][6] = 0; a1[t][7] = 0;
      if (q == 0) {
        a1[t][0] = f2bf(dirs[rc * 3 + 0]);
        a1[t][1] = f2bf(dirs[rc * 3 + 1]);
        a1[t][2] = f2bf(dirs[rc * 3 + 2]);
      }
    }

    f32x4 acc[2][4];
    #pragma unroll
    for (int t4 = 0; t4 < 4; ++t4) {
      int brow = (t4 * 16 + nl) * ROWS;
      bf16x8 bt0 = *(const bf16x8*)&W1T[brow + q * 8];
      bf16x8 bt1 = *(const bf16x8*)&W1T[brow + 32 + q * 8];
      #pragma unroll
      for (int t = 0; t < 2; ++t) {
        f32x4 z = {0.f, 0.f, 0.f, 0.f};
        z = __builtin_amdgcn_mfma_f32_16x16x32_bf16(a0[t], bt0, z, 0, 0, 0);
        z = __builtin_amdgcn_mfma_f32_16x16x32_bf16(a1[t], bt1, z, 0, 0, 0);
        acc[t][t4] = z;
      }
    }
    #pragma unroll
    for (int t = 0; t < 2; ++t)
      #pragma unroll
      for (int t4 = 0; t4 < 4; ++t4)
        #pragma unroll
        for (int i = 0; i < 4; ++i) {
          float v = fmaxf(acc[t][t4][i] + b1v[t4], 0.0f);
          H1T[wave][(t * 16 + q * 4 + i) * ROWS + t4 * 16 + nl] = f2bf(v);
        }
    __syncthreads();   // H1 visible + compiler fence (round-3 lesson)

    #pragma unroll
    for (int t4 = 0; t4 < 4; ++t4) {
      int brow = (t4 * 16 + nl) * ROWS;
      bf16x8 bt0 = *(const bf16x8*)&W2T[brow + q * 8];
      bf16x8 bt1 = *(const bf16x8*)&W2T[brow + 32 + q * 8];
      #pragma unroll
      for (int t = 0; t < 2; ++t) {
        bf16x8 h0 = *(const bf16x8*)&H1T[wave][(t * 16 + nl) * ROWS + q * 8];
        bf16x8 h1f = *(const bf16x8*)&H1T[wave][(t * 16 + nl) * ROWS + 32 + q * 8];
        f32x4 z = {0.f, 0.f, 0.f, 0.f};
        z = __builtin_amdgcn_mfma_f32_16x16x32_bf16(h0, bt0, z, 0, 0, 0);
        z = __builtin_amdgcn_mfma_f32_16x16x32_bf16(h1f, bt1, z, 0, 0, 0);
        acc[t][t4] = z;
      }
    }

    #pragma unroll
    for (int t = 0; t < 2; ++t) {
      float part[4] = {0.f, 0.f, 0.f, 0.f};
      #pragma unroll
      for (int t4 = 0; t4 < 4; ++t4)
        #pragma unroll
        for (int i = 0; i < 4; ++i) {
          float v = fmaxf(acc[t][t4][i] + b2v[t4], 0.0f);
          part[i] = fmaf(v, w3v[t4], part[i]);
        }
      #pragma unroll
      for (int s = 1; s < 16; s <<= 1) {
        #pragma unroll
        for (int i = 0; i < 4; ++i) part[i] += __shfl_xor(part[i], s, 64);
      }
      if (nl == 0) {
        int orow = wbase + t * 16 + q * 4;
        #pragma unroll
        for (int i = 0; i < 4; ++i) {
          if (orow + i < n) {
            float v = part[i] + b3s + 1.0f;
            out[order[orow + i]] = fmaxf(v, 0.0f) + log1pf(expf(-fabsf(v)));
          }
        }
      }
    }
    __syncthreads();   // WAR fence for next batch
  }
}

// ============ Fallback path A (ws >= 128MiB only): unsorted r7 ==============
__global__ __launch_bounds__(256)
void mlp_mfma3(const float* __restrict__ dirs,
               const unsigned* __restrict__ ws,
               const float* __restrict__ W1, const float* __restrict__ b1,
               const float* __restrict__ W2, const float* __restrict__ b2,
               const float* __restrict__ W3, const float* __restrict__ b3,
               float* __restrict__ out, int n)
{
  __shared__ short W1T[64 * ROWS];
  __shared__ short W2T[64 * ROWS];
  __shared__ short H1T[4][32 * ROWS];

  int tid = threadIdx.x;
  {
    int nn = tid >> 2;
    int kg = tid & 3;
    bf16x8 v1a, v1b, v2a, v2b;
    #pragma unroll
    for (int j = 0; j < 8; ++j) {
      int k0 = kg * 16 + j, k1 = kg * 16 + 8 + j;
      v1a[j] = (k0 < 32) ? f2bf(W1[(k0 + 3) * 64 + nn])
             : (k0 < 35) ? f2bf(W1[(k0 - 32) * 64 + nn]) : (short)0;
      v1b[j] = (k1 < 32) ? f2bf(W1[(k1 + 3) * 64 + nn])
             : (k1 < 35) ? f2bf(W1[(k1 - 32) * 64 + nn]) : (short)0;
      v2a[j] = f2bf(W2[k0 * 64 + nn]);
      v2b[j] = f2bf(W2[k1 * 64 + nn]);
    }
    int wo = nn * ROWS + kg * 16;
    *(bf16x8*)&W1T[wo]     = v1a;
    *(bf16x8*)&W1T[wo + 8] = v1b;
    *(bf16x8*)&W2T[wo]     = v2a;
    *(bf16x8*)&W2T[wo + 8] = v2b;
  }
  __syncthreads();

  int wave = tid >> 6, lane = tid & 63;
  int q = lane >> 4, nl = lane & 15;

  float b1v[4], b2v[4], w3v[4];
  #pragma unroll
  for (int t4 = 0; t4 < 4; ++t4) {
    b1v[t4] = b1[t4 * 16 + nl];
    b2v[t4] = b2[t4 * 16 + nl];
    w3v[t4] = W3[t4 * 16 + nl];
  }
  float b3s = b3[0];

  int blockBase = blockIdx.x * RPB;

  for (int batch = 0; batch < RPB / 128; ++batch) {
    int wbase = blockBase + batch * 128 + wave * 32;
    bf16x8 a0[2], a1[2];
    #pragma unroll
    for (int t = 0; t < 2; ++t) {
      int rr = wbase + t * 16 + nl;
      int rc = rr < n ? rr : (n - 1);
      unsigned u0 = ws[(size_t)(q * 4 + 0) * n + rc];
      unsigned u1 = ws[(size_t)(q * 4 + 1) * n + rc];
      unsigned u2 = ws[(size_t)(q * 4 + 2) * n + rc];
      unsigned u3 = ws[(size_t)(q * 4 + 3) * n + rc];
      a0[t][0] = lo16(u0); a0[t][1] = hi16(u0); a0[t][2] = lo16(u1); a0[t][3] = hi16(u1);
      a0[t][4] = lo16(u2); a0[t][5] = hi16(u2); a0[t][6] = lo16(u3); a0[t][7] = hi16(u3);
      a1[t][0] = 0; a1[t][1] = 0; a1[t][2] = 0; a1[t][3] = 0;
      a1[t][4] = 0; a1[t][5] = 0; a1[t][6] = 0; a1[t][7] = 0;
      if (q == 0) {
        a1[t][0] = f2bf(dirs[rc * 3 + 0]);
        a1[t][1] = f2bf(dirs[rc * 3 + 1]);
        a1[t][2] = f2bf(dirs[rc * 3 + 2]);
      }
    }

    f32x4 acc[2][4];
    #pragma unroll
    for (int t4 = 0; t4 < 4; ++t4) {
      int brow = (t4 * 16 + nl) * ROWS;
      bf16x8 bt0 = *(const bf16x8*)&W1T[brow + q * 8];
      bf16x8 bt1 = *(const bf16x8*)&W1T[brow + 32 + q * 8];
      #pragma unroll
      for (int t = 0; t < 2; ++t) {
        f32x4 z = {0.f, 0.f, 0.f, 0.f};
        z = __builtin_amdgcn_mfma_f32_16x16x32_bf16(a0[t], bt0, z, 0, 0, 0);
        z = __builtin_amdgcn_mfma_f32_16x16x32_bf16(a1[t], bt1, z, 0, 0, 0);
        acc[t][t4] = z;
      }
    }
    #pragma unroll
    for (int t = 0; t < 2; ++t)
      #pragma unroll
      for (int t4 = 0; t4 < 4; ++t4)
        #pragma unroll
        for (int i = 0; i < 4; ++i) {
          float v = fmaxf(acc[t][t4][i] + b1v[t4], 0.0f);
          H1T[wave][(t * 16 + q * 4 + i) * ROWS + t4 * 16 + nl] = f2bf(v);
        }
    __syncthreads();

    #pragma unroll
    for (int t4 = 0; t4 < 4; ++t4) {
      int brow = (t4 * 16 + nl) * ROWS;
      bf16x8 bt0 = *(const bf16x8*)&W2T[brow + q * 8];
      bf16x8 bt1 = *(const bf16x8*)&W2T[brow + 32 + q * 8];
      #pragma unroll
      for (int t = 0; t < 2; ++t) {
        bf16x8 h0 = *(const bf16x8*)&H1T[wave][(t * 16 + nl) * ROWS + q * 8];
        bf16x8 h1f = *(const bf16x8*)&H1T[wave][(t * 16 + nl) * ROWS + 32 + q * 8];
        f32x4 z = {0.f, 0.f, 0.f, 0.f};
        z = __builtin_amdgcn_mfma_f32_16x16x32_bf16(h0, bt0, z, 0, 0, 0);
        z = __builtin_amdgcn_mfma_f32_16x16x32_bf16(h1f, bt1, z, 0, 0, 0);
        acc[t][t4] = z;
      }
    }

    #pragma unroll
    for (int t = 0; t < 2; ++t) {
      float part[4] = {0.f, 0.f, 0.f, 0.f};
      #pragma unroll
      for (int t4 = 0; t4 < 4; ++t4)
        #pragma unroll
        for (int i = 0; i < 4; ++i) {
          float v = fmaxf(acc[t][t4][i] + b2v[t4], 0.0f);
          part[i] = fmaf(v, w3v[t4], part[i]);
        }
      #pragma unroll
      for (int s = 1; s < 16; s <<= 1) {
        #pragma unroll
        for (int i = 0; i < 4; ++i) part[i] += __shfl_xor(part[i], s, 64);
      }
      if (nl == 0) {
        int orow = wbase + t * 16 + q * 4;
        float ov[4];
        #pragma unroll
        for (int i = 0; i < 4; ++i) {
          float v = part[i] + b3s + 1.0f;
          ov[i] = fmaxf(v, 0.0f) + log1pf(expf(-fabsf(v)));
        }
        if (orow + 3 < n) {
          float4 o4; o4.x = ov[0]; o4.y = ov[1]; o4.z = ov[2]; o4.w = ov[3];
          *(float4*)&out[orow] = o4;
        } else {
          for (int i = 0; i < 4; ++i) if (orow + i < n) out[orow + i] = ov[i];
        }
      }
    }
    __syncthreads();
  }
}

// ============ Fallback path B: round-1 fused kernel (tiny ws) ===============
__global__ __launch_bounds__(256)
void sdf_fused(const float* __restrict__ dirs,
               const float* __restrict__ table,
               const float* __restrict__ W1, const float* __restrict__ b1,
               const float* __restrict__ W2, const float* __restrict__ b2,
               const float* __restrict__ W3, const float* __restrict__ b3,
               float* __restrict__ out, int n, LevelParams lp)
{
  int gid = blockIdx.x * 256 + threadIdx.x;
  if (gid >= n) return;
  float dx = dirs[gid * 3 + 0], dy = dirs[gid * 3 + 1], dz = dirs[gid * 3 + 2];
  float xx = dx * 0.49f + 0.49f, xy = dy * 0.49f + 0.49f, xz = dz * 0.49f + 0.49f;
  float h[35];
  h[0] = dx; h[1] = dy; h[2] = dz;
  #pragma unroll
  for (int l = 0; l < NL; ++l) {
    float s = lp.scale[l];
    float px = xx * s + 0.5f, py = xy * s + 0.5f, pz = xz * s + 0.5f;
    float gx = floorf(px), gy = floorf(py), gz = floorf(pz);
    float fx = px - gx, fy = py - gy, fz = pz - gz;
    unsigned ix = (unsigned)gx, iy = (unsigned)gy, iz = (unsigned)gz;
    float wx1 = fx * fx * (3.0f - 2.0f * fx);
    float wy1 = fy * fy * (3.0f - 2.0f * fy);
    float wz1 = fz * fz * (3.0f - 2.0f * fz);
    float wx0 = 1.0f - wx1, wy0 = 1.0f - wy1, wz0 = 1.0f - wz1;
    unsigned i000, i100, i010, i110, i001, i101, i011, i111;
    if ((lp.dense_mask >> l) & 1u) {
      unsigned r = lp.res[l], r2 = r * r;
      unsigned x0 = ix, x1 = ix + 1u, y0 = iy * r, y1 = y0 + r, z0 = iz * r2, z1 = z0 + r2;
      i000 = x0 + y0 + z0; i100 = x1 + y0 + z0; i010 = x0 + y1 + z0; i110 = x1 + y1 + z0;
      i001 = x0 + y0 + z1; i101 = x1 + y0 + z1; i011 = x0 + y1 + z1; i111 = x1 + y1 + z1;
    } else {
      unsigned x0 = ix, x1 = ix + 1u;
      unsigned y0 = iy * 2654435761u, y1 = y0 + 2654435761u;
      unsigned z0 = iz * 805459861u,  z1 = z0 + 805459861u;
      i000 = (x0 ^ y0 ^ z0) & TMASK; i100 = (x1 ^ y0 ^ z0) & TMASK;
      i010 = (x0 ^ y1 ^ z0) & TMASK; i110 = (x1 ^ y1 ^ z0) & TMASK;
      i001 = (x0 ^ y0 ^ z1) & TMASK; i101 = (x1 ^ y0 ^ z1) & TMASK;
      i011 = (x0 ^ y1 ^ z1) & TMASK; i111 = (x1 ^ y1 ^ z1) & TMASK;
    }
    const float2* t = (const float2*)table + (size_t)l * TSIZE;
    float2 f000 = t[i000], f100 = t[i100], f010 = t[i010], f110 = t[i110];
    float2 f001 = t[i001], f101 = t[i101], f011 = t[i011], f111 = t[i111];
    float wy0z0 = wy0 * wz0, wy1z0 = wy1 * wz0, wy0z1 = wy0 * wz1, wy1z1 = wy1 * wz1;
    float w000 = wx0 * wy0z0, w100 = wx1 * wy0z0, w010 = wx0 * wy1z0, w110 = wx1 * wy1z0;
    float w001 = wx0 * wy0z1, w101 = wx1 * wy0z1, w011 = wx0 * wy1z1, w111 = wx1 * wy1z1;
    h[3 + 2 * l] = w000 * f000.x + w100 * f100.x + w010 * f010.x + w110 * f110.x
                 + w001 * f001.x + w101 * f101.x + w011 * f011.x + w111 * f111.x;
    h[4 + 2 * l] = w000 * f000.y + w100 * f100.y + w010 * f010.y + w110 * f110.y
                 + w001 * f001.y + w101 * f101.y + w011 * f011.y + w111 * f111.y;
  }
  float h1[64];
  #pragma unroll
  for (int j = 0; j < 64; ++j) {
    float acc = b1[j];
    #pragma unroll
    for (int i = 0; i < 35; ++i) acc = fmaf(h[i], W1[i * 64 + j], acc);
    h1[j] = fmaxf(acc, 0.0f);
  }
  float h2[64];
  #pragma unroll
  for (int j = 0; j < 64; ++j) {
    float acc = b2[j];
    #pragma unroll
    for (int i = 0; i < 64; ++i) acc = fmaf(h1[i], W2[i * 64 + j], acc);
    h2[j] = fmaxf(acc, 0.0f);
  }
  float o = b3[0];
  #pragma unroll
  for (int i = 0; i < 64; ++i) o = fmaf(h2[i], W3[i], o);
  float v = o + 1.0f;
  out[gid] = fmaxf(v, 0.0f) + log1pf(expf(-fabsf(v)));
}

extern "C" void kernel_launch(void* const* d_in, const int* in_sizes, int n_in,
                              void* d_out, int out_size, void* d_ws, size_t ws_size,
                              hipStream_t stream) {
  const float* dirs  = (const float*)d_in[0];
  const float* table = (const float*)d_in[1];
  const float* W1 = (const float*)d_in[2];
  const float* b1 = (const float*)d_in[3];
  const float* W2 = (const float*)d_in[4];
  const float* b2 = (const float*)d_in[5];
  const float* W3 = (const float*)d_in[6];
  const float* b3 = (const float*)d_in[7];
  float* out = (float*)d_out;
  int n = in_sizes[0] / 3;

  LevelParams lp;
  double pls = std::exp(std::log(2048.0 / 16.0) / 15.0);
  unsigned dm = 0;
  for (int l = 0; l < NL; ++l) {
    double scale = 16.0 * std::pow(pls, (double)l) - 1.0;
    lp.scale[l] = (float)scale;
    long long res = (long long)std::ceil(scale) + 1;
    lp.res[l] = (unsigned)res;
    if (res * res * res <= (long long)TSIZE) dm |= (1u << l);
  }
  lp.dense_mask = dm;

  size_t feat_bytes  = (size_t)n * NL * 4;         // 128 MiB at n=2M
  size_t sdirs_bytes = (size_t)n * 12;
  size_t order_bytes = (size_t)n * 4;
  size_t hist_bytes  = (size_t)NBINS * 4;
  size_t bsum_bytes  = 256 * 4;
  size_t sorted_need = feat_bytes + sdirs_bytes + order_bytes + hist_bytes + bsum_bytes;

  int blocks256 = (n + 255) / 256;
  int mlp_blocks = (n + RPB - 1) / RPB;

  if (ws_size >= sorted_need) {
    char* base = (char*)d_ws;
    unsigned* feats = (unsigned*)base;
    float*    sdirs = (float*)(base + feat_bytes);
    unsigned* order = (unsigned*)(base + feat_bytes + sdirs_bytes);
    unsigned* hist  = (unsigned*)(base + feat_bytes + sdirs_bytes + order_bytes);
    unsigned* bsums = (unsigned*)(base + feat_bytes + sdirs_bytes + order_bytes + hist_bytes);

    hipMemsetAsync(hist, 0, hist_bytes, stream);
    hipLaunchKernelGGL(hist_k, dim3(blocks256), dim3(256), 0, stream, dirs, hist, n);
    hipLaunchKernelGGL(scanA_k, dim3(256), dim3(256), 0, stream, hist, bsums);
    hipLaunchKernelGGL(scanB_k, dim3(1), dim3(256), 0, stream, bsums);
    hipLaunchKernelGGL(scanC_k, dim3(256), dim3(256), 0, stream, hist, bsums);
    hipLaunchKernelGGL(scatter_k, dim3(blocks256), dim3(256), 0, stream,
                       dirs, hist, sdirs, order, n);
    hipLaunchKernelGGL(encode_k6, dim3(8 * blocks256), dim3(256), 0, stream,
                       sdirs, table, feats, n, lp);
    hipLaunchKernelGGL(mlp_mfma4, dim3(mlp_blocks), dim3(256), 0, stream,
                       sdirs, feats, order, W1, b1, W2, b2, W3, b3, out, n);
  } else if (ws_size >= feat_bytes) {
    unsigned* feats = (unsigned*)d_ws;
    hipLaunchKernelGGL(encode_k6, dim3(8 * blocks256), dim3(256), 0, stream,
                       dirs, table, feats, n, lp);
    hipLaunchKernelGGL(mlp_mfma3, dim3(mlp_blocks), dim3(256), 0, stream,
                       dirs, feats, W1, b1, W2, b2, W3, b3, out, n);
  } else {
    hipLaunchKernelGGL(sdf_fused, dim3(blocks256), dim3(256), 0, stream,
                       dirs, table, W1, b1, W2, b2, W3, b3, out, n, lp);
  }
}

// Round 10
// 926.664 us; speedup vs baseline: 1.1145x; 1.0097x over previous
//
#include <hip/hip_runtime.h>
#include <hip/hip_bf16.h>
#include <cmath>

#define NL 16
#define TSIZE (1u << 19)
#define TMASK (TSIZE - 1u)
#define NBINS (1u << 18)     // 18-bit Morton key (6 bits/axis, res 64)

typedef __attribute__((ext_vector_type(8))) short bf16x8;     // 8 bf16 (4 VGPRs)
typedef __attribute__((ext_vector_type(4))) float f32x4;

struct LevelParams {
  float scale[NL];
  unsigned res[NL];
  unsigned dense_mask;
};

static __device__ __forceinline__ short f2bf(float f) {
  __hip_bfloat16 h = __float2bfloat16(f);
  return *reinterpret_cast<short*>(&h);
}
static __device__ __forceinline__ short lo16(unsigned u) { return (short)(u & 0xffffu); }
static __device__ __forceinline__ short hi16(unsigned u) { return (short)(u >> 16); }

// Morton spread (standard 10-bit spread3; inputs are 6-bit)
static __device__ __forceinline__ unsigned spread3(unsigned x) {
  x &= 0x3FFu;
  x = (x | (x << 16)) & 0x030000FFu;
  x = (x | (x << 8))  & 0x0300F00Fu;
  x = (x | (x << 4))  & 0x030C30C3u;
  x = (x | (x << 2))  & 0x09249249u;
  return x;
}
static __device__ __forceinline__ unsigned ray_key(float dx, float dy, float dz) {
  float X0 = dx * 0.49f + 0.49f;
  float X1 = dy * 0.49f + 0.49f;
  float X2 = dz * 0.49f + 0.49f;
  unsigned qx = (unsigned)(X0 * 64.0f); qx = qx > 63u ? 63u : qx;
  unsigned qy = (unsigned)(X1 * 64.0f); qy = qy > 63u ? 63u : qy;
  unsigned qz = (unsigned)(X2 * 64.0f); qz = qz > 63u ? 63u : qz;
  return spread3(qx) | (spread3(qy) << 1) | (spread3(qz) << 2);
}

// ============ Sort pipeline: counting sort on 18-bit Morton key ============
__global__ __launch_bounds__(256)
void hist_k(const float* __restrict__ dirs, unsigned* __restrict__ hist, int n) {
  int i = blockIdx.x * 256 + threadIdx.x;
  if (i >= n) return;
  unsigned key = ray_key(dirs[i * 3 + 0], dirs[i * 3 + 1], dirs[i * 3 + 2]);
  atomicAdd(&hist[key], 1u);
}

// Hierarchical scan (r8 lesson: single-block scan over 256K bins was ~400 us
// serialized on one CU). 256 blocks x 256 thr x 4 bins = 256K.
__global__ __launch_bounds__(256)
void scanA_k(unsigned* __restrict__ hist, unsigned* __restrict__ blockSums) {
  __shared__ unsigned sums[256];
  int bid = blockIdx.x, t = threadIdx.x;
  unsigned base = (unsigned)bid * 1024u + (unsigned)t * 4u;
  uint4 c = *(uint4*)&hist[base];
  unsigned s = c.x + c.y + c.z + c.w;
  sums[t] = s;
  __syncthreads();
  for (int off = 1; off < 256; off <<= 1) {   // Hillis-Steele inclusive
    unsigned v = (t >= off) ? sums[t - off] : 0u;
    __syncthreads();
    sums[t] += v;
    __syncthreads();
  }
  unsigned excl = sums[t] - s;                // exclusive prefix within block
  uint4 o;
  o.x = excl;
  o.y = excl + c.x;
  o.z = excl + c.x + c.y;
  o.w = excl + c.x + c.y + c.z;
  *(uint4*)&hist[base] = o;
  if (t == 255) blockSums[bid] = sums[255];   // block total
}

__global__ __launch_bounds__(256)
void scanB_k(unsigned* __restrict__ blockSums) {   // 1 block, 256 entries
  __shared__ unsigned sums[256];
  int t = threadIdx.x;
  unsigned s = blockSums[t];
  sums[t] = s;
  __syncthreads();
  for (int off = 1; off < 256; off <<= 1) {
    unsigned v = (t >= off) ? sums[t - off] : 0u;
    __syncthreads();
    sums[t] += v;
    __syncthreads();
  }
  blockSums[t] = sums[t] - s;                 // exclusive
}

__global__ __launch_bounds__(256)
void scanC_k(unsigned* __restrict__ hist, const unsigned* __restrict__ blockSums) {
  int bid = blockIdx.x, t = threadIdx.x;
  unsigned off = blockSums[bid];
  unsigned base = (unsigned)bid * 1024u + (unsigned)t * 4u;
  uint4 c = *(uint4*)&hist[base];
  c.x += off; c.y += off; c.z += off; c.w += off;
  *(uint4*)&hist[base] = c;
}

__global__ __launch_bounds__(256)
void scatter_k(const float* __restrict__ dirs, unsigned* __restrict__ hist,
               float* __restrict__ sdirs, unsigned* __restrict__ order, int n) {
  int i = blockIdx.x * 256 + threadIdx.x;
  if (i >= n) return;
  float dx = dirs[i * 3 + 0], dy = dirs[i * 3 + 1], dz = dirs[i * 3 + 2];
  unsigned key = ray_key(dx, dy, dz);
  unsigned pos = atomicAdd(&hist[key], 1u);
  sdirs[pos * 3 + 0] = dx;
  sdirs[pos * 3 + 1] = dy;
  sdirs[pos * 3 + 2] = dz;
  order[pos] = i;
}

// ============ Encode: 1 ray x 2 levels (p, p+8) per thread, DE-PINNED. ======
// r9 lesson: the XCD pin (r4 win) became the bottleneck after sorting —
// levels 13-15 (~4 unique lines/ray, little dedup at fine resolution) were
// confined to 3 XCDs while the other 5 idled (makespan 331 us == 32-CU math).
// New mapping spreads every level-pair across all 8 XCDs:
//   pair = (b>>3)&7, chunk = (b>>6)*8 + (b&7)  -> for fixed pair, b%8 covers
// all XCD slots; coverage of (pair, chunk) exact. Sorted input keeps the
// instantaneous working set tiny, so per-XCD L2 pinning is no longer needed.
__global__ __launch_bounds__(256)
void encode_k7(const float* __restrict__ dirs,
               const float* __restrict__ table,
               unsigned* __restrict__ ws,
               int n, LevelParams lp)
{
  int b = blockIdx.x;
  int l0 = (b >> 3) & 7;                        // level pair -> levels l0, l0+8
  int chunk = ((b >> 6) << 3) + (b & 7);        // XCD slot decoupled from pair
  int ray = chunk * 256 + threadIdx.x;
  if (ray >= n) return;

  float X0 = dirs[ray * 3 + 0] * 0.49f + 0.49f;
  float X1 = dirs[ray * 3 + 1] * 0.49f + 0.49f;
  float X2 = dirs[ray * 3 + 2] * 0.49f + 0.49f;

  float wa0[2][3], wa1[2][3];
  bool dns[2];
  unsigned didx[2][8];
  unsigned par[2][4];
  const float2* tb[2];

  #pragma unroll
  for (int g = 0; g < 2; ++g) {
    int level = l0 + g * 8;
    float s = lp.scale[level];
    unsigned r = lp.res[level];
    dns[g] = (lp.dense_mask >> level) & 1u;

    float px = X0 * s + 0.5f, py = X1 * s + 0.5f, pz = X2 * s + 0.5f;
    float gx = floorf(px), gy = floorf(py), gz = floorf(pz);
    float fx = px - gx, fy = py - gy, fz = pz - gz;
    unsigned ix = (unsigned)gx, iy = (unsigned)gy, iz = (unsigned)gz;

    wa1[g][0] = fx * fx * (3.0f - 2.0f * fx);
    wa1[g][1] = fy * fy * (3.0f - 2.0f * fy);
    wa1[g][2] = fz * fz * (3.0f - 2.0f * fz);
    wa0[g][0] = 1.0f - wa1[g][0];
    wa0[g][1] = 1.0f - wa1[g][1];
    wa0[g][2] = 1.0f - wa1[g][2];

    if (dns[g]) {
      unsigned r2 = r * r;
      unsigned x0 = ix, x1 = ix + 1u;
      unsigned y0 = iy * r, y1 = y0 + r;
      unsigned z0 = iz * r2, z1 = z0 + r2;
      didx[g][0] = x0 + y0 + z0; didx[g][1] = x1 + y0 + z0;
      didx[g][2] = x0 + y1 + z0; didx[g][3] = x1 + y1 + z0;
      didx[g][4] = x0 + y0 + z1; didx[g][5] = x1 + y0 + z1;
      didx[g][6] = x0 + y1 + z1; didx[g][7] = x1 + y1 + z1;
    } else {
      unsigned y0 = iy * 2654435761u, y1 = y0 + 2654435761u;  // uint32 wrap == ref
      unsigned z0 = iz * 805459861u,  z1 = z0 + 805459861u;
      unsigned p0 = (ix ^ y0 ^ z0) & TMASK;
      unsigned p1 = (ix ^ y1 ^ z0) & TMASK;
      unsigned p2 = (ix ^ y0 ^ z1) & TMASK;
      unsigned p3 = (ix ^ y1 ^ z1) & TMASK;
      didx[g][0] = p0 >> 1; didx[g][1] = p1 >> 1;
      didx[g][2] = p2 >> 1; didx[g][3] = p3 >> 1;
      par[g][0] = p0 & 1u; par[g][1] = p1 & 1u;
      par[g][2] = p2 & 1u; par[g][3] = p3 & 1u;
    }
    tb[g] = (const float2*)table + (size_t)level * TSIZE;
  }

  float2 v[2][8];
  float4 f4[2][4];
  #pragma unroll
  for (int g = 0; g < 2; ++g) {
    if (dns[g]) {
      #pragma unroll
      for (int c = 0; c < 8; ++c) v[g][c] = tb[g][didx[g][c]];
    } else {
      const float4* t4p = (const float4*)tb[g];
      #pragma unroll
      for (int c = 0; c < 4; ++c) f4[g][c] = t4p[didx[g][c]];
    }
  }
  #pragma unroll
  for (int g = 0; g < 2; ++g) {
    if (!dns[g]) {
      #pragma unroll
      for (int c = 0; c < 4; ++c) {
        float2 even, odd;
        even.x = f4[g][c].x; even.y = f4[g][c].y;
        odd.x  = f4[g][c].z; odd.y  = f4[g][c].w;
        bool o = par[g][c] != 0;
        v[g][2 * c]     = o ? odd : even;
        v[g][2 * c + 1] = o ? even : odd;
      }
    }
  }

  #pragma unroll
  for (int g = 0; g < 2; ++g) {
    float wx0 = wa0[g][0], wx1 = wa1[g][0];
    float wy0 = wa0[g][1], wy1 = wa1[g][1];
    float wz0 = wa0[g][2], wz1 = wa1[g][2];
    float wy0z0 = wy0 * wz0, wy1z0 = wy1 * wz0, wy0z1 = wy0 * wz1, wy1z1 = wy1 * wz1;
    float w000 = wx0 * wy0z0, w100 = wx1 * wy0z0;
    float w010 = wx0 * wy1z0, w110 = wx1 * wy1z0;
    float w001 = wx0 * wy0z1, w101 = wx1 * wy0z1;
    float w011 = wx0 * wy1z1, w111 = wx1 * wy1z1;

    float a0 = w000 * v[g][0].x + w100 * v[g][1].x + w010 * v[g][2].x + w110 * v[g][3].x
             + w001 * v[g][4].x + w101 * v[g][5].x + w011 * v[g][6].x + w111 * v[g][7].x;
    float a1 = w000 * v[g][0].y + w100 * v[g][1].y + w010 * v[g][2].y + w110 * v[g][3].y
             + w001 * v[g][4].y + w101 * v[g][5].y + w011 * v[g][6].y + w111 * v[g][7].y;

    int level = l0 + g * 8;
    unsigned packed = ((unsigned)f2bf(a0) & 0xffffu) | (((unsigned)f2bf(a1) & 0xffffu) << 16);
    ws[(size_t)level * n + ray] = packed;
  }
}

// ============ MLP via bf16 MFMA; sorted space, scatter via order[] ==========
#define RPB 512
#define ROWS 72

__global__ __launch_bounds__(256)
void mlp_mfma4(const float* __restrict__ dirs,       // SORTED dirs
               const unsigned* __restrict__ ws,      // [16][n] bf16x2, sorted
               const unsigned* __restrict__ order,   // sorted pos -> orig ray
               const float* __restrict__ W1, const float* __restrict__ b1,
               const float* __restrict__ W2, const float* __restrict__ b2,
               const float* __restrict__ W3, const float* __restrict__ b3,
               float* __restrict__ out, int n)
{
  __shared__ short W1T[64 * ROWS];
  __shared__ short W2T[64 * ROWS];
  __shared__ short H1T[4][32 * ROWS];

  int tid = threadIdx.x;
  {
    int nn = tid >> 2;
    int kg = tid & 3;
    bf16x8 v1a, v1b, v2a, v2b;
    #pragma unroll
    for (int j = 0; j < 8; ++j) {
      int k0 = kg * 16 + j, k1 = kg * 16 + 8 + j;
      v1a[j] = (k0 < 32) ? f2bf(W1[(k0 + 3) * 64 + nn])
             : (k0 < 35) ? f2bf(W1[(k0 - 32) * 64 + nn]) : (short)0;
      v1b[j] = (k1 < 32) ? f2bf(W1[(k1 + 3) * 64 + nn])
             : (k1 < 35) ? f2bf(W1[(k1 - 32) * 64 + nn]) : (short)0;
      v2a[j] = f2bf(W2[k0 * 64 + nn]);
      v2b[j] = f2bf(W2[k1 * 64 + nn]);
    }
    int wo = nn * ROWS + kg * 16;
    *(bf16x8*)&W1T[wo]     = v1a;
    *(bf16x8*)&W1T[wo + 8] = v1b;
    *(bf16x8*)&W2T[wo]     = v2a;
    *(bf16x8*)&W2T[wo + 8] = v2b;
  }
  __syncthreads();

  int wave = tid >> 6, lane = tid & 63;
  int q = lane >> 4, nl = lane & 15;

  float b1v[4], b2v[4], w3v[4];
  #pragma unroll
  for (int t4 = 0; t4 < 4; ++t4) {
    b1v[t4] = b1[t4 * 16 + nl];
    b2v[t4] = b2[t4 * 16 + nl];
    w3v[t4] = W3[t4 * 16 + nl];
  }
  float b3s = b3[0];

  int blockBase = blockIdx.x * RPB;

  for (int batch = 0; batch < RPB / 128; ++batch) {
    int wbase = blockBase + batch * 128 + wave * 32;

    bf16x8 a0[2], a1[2];
    #pragma unroll
    for (int t = 0; t < 2; ++t) {
      int rr = wbase + t * 16 + nl;
      int rc = rr < n ? rr : (n - 1);
      unsigned u0 = ws[(size_t)(q * 4 + 0) * n + rc];
      unsigned u1 = ws[(size_t)(q * 4 + 1) * n + rc];
      unsigned u2 = ws[(size_t)(q * 4 + 2) * n + rc];
      unsigned u3 = ws[(size_t)(q * 4 + 3) * n + rc];
      a0[t][0] = lo16(u0); a0[t][1] = hi16(u0); a0[t][2] = lo16(u1); a0[t][3] = hi16(u1);
      a0[t][4] = lo16(u2); a0[t][5] = hi16(u2); a0[t][6] = lo16(u3); a0[t][7] = hi16(u3);
      a1[t][0] = 0; a1[t][1] = 0; a1[t][2] = 0; a1[t][3] = 0;
      a1[t][4] = 0; a1[t][5] = 0; a1[t][6] = 0; a1[t][7] = 0;
      if (q == 0) {
        a1[t][0] = f2bf(dirs[rc * 3 + 0]);
        a1[t][1] = f2bf(dirs[rc * 3 + 1]);
        a1[t][2] = f2bf(dirs[rc * 3 + 2]);
      }
    }

    f32x4 acc[2][4];
    #pragma unroll
    for (int t4 = 0; t4 < 4; ++t4) {
      int brow = (t4 * 16 + nl) * ROWS;
      bf16x8 bt0 = *(const bf16x8*)&W1T[brow + q * 8];
      bf16x8 bt1 = *(const bf16x8*)&W1T[brow + 32 + q * 8];
      #pragma unroll
      for (int t = 0; t < 2; ++t) {
        f32x4 z = {0.f, 0.f, 0.f, 0.f};
        z = __builtin_amdgcn_mfma_f32_16x16x32_bf16(a0[t], bt0, z, 0, 0, 0);
        z = __builtin_amdgcn_mfma_f32_16x16x32_bf16(a1[t], bt1, z, 0, 0, 0);
        acc[t][t4] = z;
      }
    }
    #pragma unroll
    for (int t = 0; t < 2; ++t)
      #pragma unroll
      for (int t4 = 0; t4 < 4; ++t4)
        #pragma unroll
        for (int i = 0; i < 4; ++i) {
          float v = fmaxf(acc[t][t4][i] + b1v[t4], 0.0f);
          H1T[wave][(t * 16 + q * 4 + i) * ROWS + t4 * 16 + nl] = f2bf(v);
        }
    __syncthreads();   // H1 visible + compiler fence (round-3 lesson)

    #pragma unroll
    for (int t4 = 0; t4 < 4; ++t4) {
      int brow = (t4 * 16 + nl) * ROWS;
      bf16x8 bt0 = *(const bf16x8*)&W2T[brow + q * 8];
      bf16x8 bt1 = *(const bf16x8*)&W2T[brow + 32 + q * 8];
      #pragma unroll
      for (int t = 0; t < 2; ++t) {
        bf16x8 h0 = *(const bf16x8*)&H1T[wave][(t * 16 + nl) * ROWS + q * 8];
        bf16x8 h1f = *(const bf16x8*)&H1T[wave][(t * 16 + nl) * ROWS + 32 + q * 8];
        f32x4 z = {0.f, 0.f, 0.f, 0.f};
        z = __builtin_amdgcn_mfma_f32_16x16x32_bf16(h0, bt0, z, 0, 0, 0);
        z = __builtin_amdgcn_mfma_f32_16x16x32_bf16(h1f, bt1, z, 0, 0, 0);
        acc[t][t4] = z;
      }
    }

    #pragma unroll
    for (int t = 0; t < 2; ++t) {
      float part[4] = {0.f, 0.f, 0.f, 0.f};
      #pragma unroll
      for (int t4 = 0; t4 < 4; ++t4)
        #pragma unroll
        for (int i = 0; i < 4; ++i) {
          float v = fmaxf(acc[t][t4][i] + b2v[t4], 0.0f);
          part[i] = fmaf(v, w3v[t4], part[i]);
        }
      #pragma unroll
      for (int s = 1; s < 16; s <<= 1) {
        #pragma unroll
        for (int i = 0; i < 4; ++i) part[i] += __shfl_xor(part[i], s, 64);
      }
      if (nl == 0) {
        int orow = wbase + t * 16 + q * 4;
        #pragma unroll
        for (int i = 0; i < 4; ++i) {
          if (orow + i < n) {
            float v = part[i] + b3s + 1.0f;
            out[order[orow + i]] = fmaxf(v, 0.0f) + log1pf(expf(-fabsf(v)));
          }
        }
      }
    }
    __syncthreads();   // WAR fence for next batch
  }
}

// ============ Fallback path A (ws >= 128MiB only): unsorted ==============
__global__ __launch_bounds__(256)
void mlp_mfma3(const float* __restrict__ dirs,
               const unsigned* __restrict__ ws,
               const float* __restrict__ W1, const float* __restrict__ b1,
               const float* __restrict__ W2, const float* __restrict__ b2,
               const float* __restrict__ W3, const float* __restrict__ b3,
               float* __restrict__ out, int n)
{
  __shared__ short W1T[64 * ROWS];
  __shared__ short W2T[64 * ROWS];
  __shared__ short H1T[4][32 * ROWS];

  int tid = threadIdx.x;
  {
    int nn = tid >> 2;
    int kg = tid & 3;
    bf16x8 v1a, v1b, v2a, v2b;
    #pragma unroll
    for (int j = 0; j < 8; ++j) {
      int k0 = kg * 16 + j, k1 = kg * 16 + 8 + j;
      v1a[j] = (k0 < 32) ? f2bf(W1[(k0 + 3) * 64 + nn])
             : (k0 < 35) ? f2bf(W1[(k0 - 32) * 64 + nn]) : (short)0;
      v1b[j] = (k1 < 32) ? f2bf(W1[(k1 + 3) * 64 + nn])
             : (k1 < 35) ? f2bf(W1[(k1 - 32) * 64 + nn]) : (short)0;
      v2a[j] = f2bf(W2[k0 * 64 + nn]);
      v2b[j] = f2bf(W2[k1 * 64 + nn]);
    }
    int wo = nn * ROWS + kg * 16;
    *(bf16x8*)&W1T[wo]     = v1a;
    *(bf16x8*)&W1T[wo + 8] = v1b;
    *(bf16x8*)&W2T[wo]     = v2a;
    *(bf16x8*)&W2T[wo + 8] = v2b;
  }
  __syncthreads();

  int wave = tid >> 6, lane = tid & 63;
  int q = lane >> 4, nl = lane & 15;

  float b1v[4], b2v[4], w3v[4];
  #pragma unroll
  for (int t4 = 0; t4 < 4; ++t4) {
    b1v[t4] = b1[t4 * 16 + nl];
    b2v[t4] = b2[t4 * 16 + nl];
    w3v[t4] = W3[t4 * 16 + nl];
  }
  float b3s = b3[0];

  int blockBase = blockIdx.x * RPB;

  for (int batch = 0; batch < RPB / 128; ++batch) {
    int wbase = blockBase + batch * 128 + wave * 32;
    bf16x8 a0[2], a1[2];
    #pragma unroll
    for (int t = 0; t < 2; ++t) {
      int rr = wbase + t * 16 + nl;
      int rc = rr < n ? rr : (n - 1);
      unsigned u0 = ws[(size_t)(q * 4 + 0) * n + rc];
      unsigned u1 = ws[(size_t)(q * 4 + 1) * n + rc];
      unsigned u2 = ws[(size_t)(q * 4 + 2) * n + rc];
      unsigned u3 = ws[(size_t)(q * 4 + 3) * n + rc];
      a0[t][0] = lo16(u0); a0[t][1] = hi16(u0); a0[t][2] = lo16(u1); a0[t][3] = hi16(u1);
      a0[t][4] = lo16(u2); a0[t][5] = hi16(u2); a0[t][6] = lo16(u3); a0[t][7] = hi16(u3);
      a1[t][0] = 0; a1[t][1] = 0; a1[t][2] = 0; a1[t][3] = 0;
      a1[t][4] = 0; a1[t][5] = 0; a1[t][6] = 0; a1[t][7] = 0;
      if (q == 0) {
        a1[t][0] = f2bf(dirs[rc * 3 + 0]);
        a1[t][1] = f2bf(dirs[rc * 3 + 1]);
        a1[t][2] = f2bf(dirs[rc * 3 + 2]);
      }
    }

    f32x4 acc[2][4];
    #pragma unroll
    for (int t4 = 0; t4 < 4; ++t4) {
      int brow = (t4 * 16 + nl) * ROWS;
      bf16x8 bt0 = *(const bf16x8*)&W1T[brow + q * 8];
      bf16x8 bt1 = *(const bf16x8*)&W1T[brow + 32 + q * 8];
      #pragma unroll
      for (int t = 0; t < 2; ++t) {
        f32x4 z = {0.f, 0.f, 0.f, 0.f};
        z = __builtin_amdgcn_mfma_f32_16x16x32_bf16(a0[t], bt0, z, 0, 0, 0);
        z = __builtin_amdgcn_mfma_f32_16x16x32_bf16(a1[t], bt1, z, 0, 0, 0);
        acc[t][t4] = z;
      }
    }
    #pragma unroll
    for (int t = 0; t < 2; ++t)
      #pragma unroll
      for (int t4 = 0; t4 < 4; ++t4)
        #pragma unroll
        for (int i = 0; i < 4; ++i) {
          float v = fmaxf(acc[t][t4][i] + b1v[t4], 0.0f);
          H1T[wave][(t * 16 + q * 4 + i) * ROWS + t4 * 16 + nl] = f2bf(v);
        }
    __syncthreads();

    #pragma unroll
    for (int t4 = 0; t4 < 4; ++t4) {
      int brow = (t4 * 16 + nl) * ROWS;
      bf16x8 bt0 = *(const bf16x8*)&W2T[brow + q * 8];
      bf16x8 bt1 = *(const bf16x8*)&W2T[brow + 32 + q * 8];
      #pragma unroll
      for (int t = 0; t < 2; ++t) {
        bf16x8 h0 = *(const bf16x8*)&H1T[wave][(t * 16 + nl) * ROWS + q * 8];
        bf16x8 h1f = *(const bf16x8*)&H1T[wave][(t * 16 + nl) * ROWS + 32 + q * 8];
        f32x4 z = {0.f, 0.f, 0.f, 0.f};
        z = __builtin_amdgcn_mfma_f32_16x16x32_bf16(h0, bt0, z, 0, 0, 0);
        z = __builtin_amdgcn_mfma_f32_16x16x32_bf16(h1f, bt1, z, 0, 0, 0);
        acc[t][t4] = z;
      }
    }

    #pragma unroll
    for (int t = 0; t < 2; ++t) {
      float part[4] = {0.f, 0.f, 0.f, 0.f};
      #pragma unroll
      for (int t4 = 0; t4 < 4; ++t4)
        #pragma unroll
        for (int i = 0; i < 4; ++i) {
          float v = fmaxf(acc[t][t4][i] + b2v[t4], 0.0f);
          part[i] = fmaf(v, w3v[t4], part[i]);
        }
      #pragma unroll
      for (int s = 1; s < 16; s <<= 1) {
        #pragma unroll
        for (int i = 0; i < 4; ++i) part[i] += __shfl_xor(part[i], s, 64);
      }
      if (nl == 0) {
        int orow = wbase + t * 16 + q * 4;
        float ov[4];
        #pragma unroll
        for (int i = 0; i < 4; ++i) {
          float v = part[i] + b3s + 1.0f;
          ov[i] = fmaxf(v, 0.0f) + log1pf(expf(-fabsf(v)));
        }
        if (orow + 3 < n) {
          float4 o4; o4.x = ov[0]; o4.y = ov[1]; o4.z = ov[2]; o4.w = ov[3];
          *(float4*)&out[orow] = o4;
        } else {
          for (int i = 0; i < 4; ++i) if (orow + i < n) out[orow + i] = ov[i];
        }
      }
    }
    __syncthreads();
  }
}

// ============ Fallback path B: round-1 fused kernel (tiny ws) ===============
__global__ __launch_bounds__(256)
void sdf_fused(const float* __restrict__ dirs,
               const float* __restrict__ table,
               const float* __restrict__ W1, const float* __restrict__ b1,
               const float* __restrict__ W2, const float* __restrict__ b2,
               const float* __restrict__ W3, const float* __restrict__ b3,
               float* __restrict__ out, int n, LevelParams lp)
{
  int gid = blockIdx.x * 256 + threadIdx.x;
  if (gid >= n) return;
  float dx = dirs[gid * 3 + 0], dy = dirs[gid * 3 + 1], dz = dirs[gid * 3 + 2];
  float xx = dx * 0.49f + 0.49f, xy = dy * 0.49f + 0.49f, xz = dz * 0.49f + 0.49f;
  float h[35];
  h[0] = dx; h[1] = dy; h[2] = dz;
  #pragma unroll
  for (int l = 0; l < NL; ++l) {
    float s = lp.scale[l];
    float px = xx * s + 0.5f, py = xy * s + 0.5f, pz = xz * s + 0.5f;
    float gx = floorf(px), gy = floorf(py), gz = floorf(pz);
    float fx = px - gx, fy = py - gy, fz = pz - gz;
    unsigned ix = (unsigned)gx, iy = (unsigned)gy, iz = (unsigned)gz;
    float wx1 = fx * fx * (3.0f - 2.0f * fx);
    float wy1 = fy * fy * (3.0f - 2.0f * fy);
    float wz1 = fz * fz * (3.0f - 2.0f * fz);
    float wx0 = 1.0f - wx1, wy0 = 1.0f - wy1, wz0 = 1.0f - wz1;
    unsigned i000, i100, i010, i110, i001, i101, i011, i111;
    if ((lp.dense_mask >> l) & 1u) {
      unsigned r = lp.res[l], r2 = r * r;
      unsigned x0 = ix, x1 = ix + 1u, y0 = iy * r, y1 = y0 + r, z0 = iz * r2, z1 = z0 + r2;
      i000 = x0 + y0 + z0; i100 = x1 + y0 + z0; i010 = x0 + y1 + z0; i110 = x1 + y1 + z0;
      i001 = x0 + y0 + z1; i101 = x1 + y0 + z1; i011 = x0 + y1 + z1; i111 = x1 + y1 + z1;
    } else {
      unsigned x0 = ix, x1 = ix + 1u;
      unsigned y0 = iy * 2654435761u, y1 = y0 + 2654435761u;
      unsigned z0 = iz * 805459861u,  z1 = z0 + 805459861u;
      i000 = (x0 ^ y0 ^ z0) & TMASK; i100 = (x1 ^ y0 ^ z0) & TMASK;
      i010 = (x0 ^ y1 ^ z0) & TMASK; i110 = (x1 ^ y1 ^ z0) & TMASK;
      i001 = (x0 ^ y0 ^ z1) & TMASK; i101 = (x1 ^ y0 ^ z1) & TMASK;
      i011 = (x0 ^ y1 ^ z1) & TMASK; i111 = (x1 ^ y1 ^ z1) & TMASK;
    }
    const float2* t = (const float2*)table + (size_t)l * TSIZE;
    float2 f000 = t[i000], f100 = t[i100], f010 = t[i010], f110 = t[i110];
    float2 f001 = t[i001], f101 = t[i101], f011 = t[i011], f111 = t[i111];
    float wy0z0 = wy0 * wz0, wy1z0 = wy1 * wz0, wy0z1 = wy0 * wz1, wy1z1 = wy1 * wz1;
    float w000 = wx0 * wy0z0, w100 = wx1 * wy0z0, w010 = wx0 * wy1z0, w110 = wx1 * wy1z0;
    float w001 = wx0 * wy0z1, w101 = wx1 * wy0z1, w011 = wx0 * wy1z1, w111 = wx1 * wy1z1;
    h[3 + 2 * l] = w000 * f000.x + w100 * f100.x + w010 * f010.x + w110 * f110.x
                 + w001 * f001.x + w101 * f101.x + w011 * f011.x + w111 * f111.x;
    h[4 + 2 * l] = w000 * f000.y + w100 * f100.y + w010 * f010.y + w110 * f110.y
                 + w001 * f001.y + w101 * f101.y + w011 * f011.y + w111 * f111.y;
  }
  float h1[64];
  #pragma unroll
  for (int j = 0; j < 64; ++j) {
    float acc = b1[j];
    #pragma unroll
    for (int i = 0; i < 35; ++i) acc = fmaf(h[i], W1[i * 64 + j], acc);
    h1[j] = fmaxf(acc, 0.0f);
  }
  float h2[64];
  #pragma unroll
  for (int j = 0; j < 64; ++j) {
    float acc = b2[j];
    #pragma unroll
    for (int i = 0; i < 64; ++i) acc = fmaf(h1[i], W2[i * 64 + j], acc);
    h2[j] = fmaxf(acc, 0.0f);
  }
  float o = b3[0];
  #pragma unroll
  for (int i = 0; i < 64; ++i) o = fmaf(h2[i], W3[i], o);
  float v = o + 1.0f;
  out[gid] = fmaxf(v, 0.0f) + log1pf(expf(-fabsf(v)));
}

extern "C" void kernel_launch(void* const* d_in, const int* in_sizes, int n_in,
                              void* d_out, int out_size, void* d_ws, size_t ws_size,
                              hipStream_t stream) {
  const float* dirs  = (const float*)d_in[0];
  const float* table = (const float*)d_in[1];
  const float* W1 = (const float*)d_in[2];
  const float* b1 = (const float*)d_in[3];
  const float* W2 = (const float*)d_in[4];
  const float* b2 = (const float*)d_in[5];
  const float* W3 = (const float*)d_in[6];
  const float* b3 = (const float*)d_in[7];
  float* out = (float*)d_out;
  int n = in_sizes[0] / 3;

  LevelParams lp;
  double pls = std::exp(std::log(2048.0 / 16.0) / 15.0);
  unsigned dm = 0;
  for (int l = 0; l < NL; ++l) {
    double scale = 16.0 * std::pow(pls, (double)l) - 1.0;
    lp.scale[l] = (float)scale;
    long long res = (long long)std::ceil(scale) + 1;
    lp.res[l] = (unsigned)res;
    if (res * res * res <= (long long)TSIZE) dm |= (1u << l);
  }
  lp.dense_mask = dm;

  size_t feat_bytes  = (size_t)n * NL * 4;         // 128 MiB at n=2M
  size_t sdirs_bytes = (size_t)n * 12;
  size_t order_bytes = (size_t)n * 4;
  size_t hist_bytes  = (size_t)NBINS * 4;
  size_t bsum_bytes  = 256 * 4;
  size_t sorted_need = feat_bytes + sdirs_bytes + order_bytes + hist_bytes + bsum_bytes;

  int blocks256 = (n + 255) / 256;
  int mlp_blocks = (n + RPB - 1) / RPB;
  // encode_k7 grid: pair=(b>>3)&7, chunk=(b>>6)*8+(b&7); need 8*ceil(chunks/8)*8 blocks
  int chunks8 = ((blocks256 + 7) / 8) * 8;
  int enc_grid = 8 * chunks8;

  if (ws_size >= sorted_need) {
    char* base = (char*)d_ws;
    unsigned* feats = (unsigned*)base;
    float*    sdirs = (float*)(base + feat_bytes);
    unsigned* order = (unsigned*)(base + feat_bytes + sdirs_bytes);
    unsigned* hist  = (unsigned*)(base + feat_bytes + sdirs_bytes + order_bytes);
    unsigned* bsums = (unsigned*)(base + feat_bytes + sdirs_bytes + order_bytes + hist_bytes);

    hipMemsetAsync(hist, 0, hist_bytes, stream);
    hipLaunchKernelGGL(hist_k, dim3(blocks256), dim3(256), 0, stream, dirs, hist, n);
    hipLaunchKernelGGL(scanA_k, dim3(256), dim3(256), 0, stream, hist, bsums);
    hipLaunchKernelGGL(scanB_k, dim3(1), dim3(256), 0, stream, bsums);
    hipLaunchKernelGGL(scanC_k, dim3(256), dim3(256), 0, stream, hist, bsums);
    hipLaunchKernelGGL(scatter_k, dim3(blocks256), dim3(256), 0, stream,
                       dirs, hist, sdirs, order, n);
    hipLaunchKernelGGL(encode_k7, dim3(enc_grid), dim3(256), 0, stream,
                       sdirs, table, feats, n, lp);
    hipLaunchKernelGGL(mlp_mfma4, dim3(mlp_blocks), dim3(256), 0, stream,
                       sdirs, feats, order, W1, b1, W2, b2, W3, b3, out, n);
  } else if (ws_size >= feat_bytes) {
    unsigned* feats = (unsigned*)d_ws;
    hipLaunchKernelGGL(encode_k7, dim3(enc_grid), dim3(256), 0, stream,
                       dirs, table, feats, n, lp);
    hipLaunchKernelGGL(mlp_mfma3, dim3(mlp_blocks), dim3(256), 0, stream,
                       dirs, feats, W1, b1, W2, b2, W3, b3, out, n);
  } else {
    hipLaunchKernelGGL(sdf_fused, dim3(blocks256), dim3(256), 0, stream,
                       dirs, table, W1, b1, W2, b2, W3, b3, out, n, lp);
  }
}

// Round 11
// 907.593 us; speedup vs baseline: 1.1379x; 1.0210x over previous
//
#include <hip/hip_runtime.h>
#include <hip/hip_bf16.h>
#include <cmath>

#define NL 16
#define TSIZE (1u << 19)
#define TMASK (TSIZE - 1u)
#define NBINS (1u << 18)     // 18-bit Morton key (6 bits/axis, res 64)

typedef __attribute__((ext_vector_type(8))) short bf16x8;     // 8 bf16 (4 VGPRs)
typedef __attribute__((ext_vector_type(4))) float f32x4;

struct LevelParams {
  float scale[NL];
  unsigned res[NL];
  unsigned dense_mask;
};

static __device__ __forceinline__ short f2bf(float f) {
  __hip_bfloat16 h = __float2bfloat16(f);
  return *reinterpret_cast<short*>(&h);
}
static __device__ __forceinline__ short lo16(unsigned u) { return (short)(u & 0xffffu); }
static __device__ __forceinline__ short hi16(unsigned u) { return (short)(u >> 16); }

static __device__ __forceinline__ unsigned spread3(unsigned x) {
  x &= 0x3FFu;
  x = (x | (x << 16)) & 0x030000FFu;
  x = (x | (x << 8))  & 0x0300F00Fu;
  x = (x | (x << 4))  & 0x030C30C3u;
  x = (x | (x << 2))  & 0x09249249u;
  return x;
}
static __device__ __forceinline__ unsigned ray_key(float dx, float dy, float dz) {
  float X0 = dx * 0.49f + 0.49f;
  float X1 = dy * 0.49f + 0.49f;
  float X2 = dz * 0.49f + 0.49f;
  unsigned qx = (unsigned)(X0 * 64.0f); qx = qx > 63u ? 63u : qx;
  unsigned qy = (unsigned)(X1 * 64.0f); qy = qy > 63u ? 63u : qy;
  unsigned qz = (unsigned)(X2 * 64.0f); qz = qz > 63u ? 63u : qz;
  return spread3(qx) | (spread3(qy) << 1) | (spread3(qz) << 2);
}

// ============ Sort pipeline (verified r9/r10) ============
__global__ __launch_bounds__(256)
void hist_k(const float* __restrict__ dirs, unsigned* __restrict__ hist, int n) {
  int i = blockIdx.x * 256 + threadIdx.x;
  if (i >= n) return;
  unsigned key = ray_key(dirs[i * 3 + 0], dirs[i * 3 + 1], dirs[i * 3 + 2]);
  atomicAdd(&hist[key], 1u);
}

__global__ __launch_bounds__(256)
void scanA_k(unsigned* __restrict__ hist, unsigned* __restrict__ blockSums) {
  __shared__ unsigned sums[256];
  int bid = blockIdx.x, t = threadIdx.x;
  unsigned base = (unsigned)bid * 1024u + (unsigned)t * 4u;
  uint4 c = *(uint4*)&hist[base];
  unsigned s = c.x + c.y + c.z + c.w;
  sums[t] = s;
  __syncthreads();
  for (int off = 1; off < 256; off <<= 1) {
    unsigned v = (t >= off) ? sums[t - off] : 0u;
    __syncthreads();
    sums[t] += v;
    __syncthreads();
  }
  unsigned excl = sums[t] - s;
  uint4 o;
  o.x = excl;
  o.y = excl + c.x;
  o.z = excl + c.x + c.y;
  o.w = excl + c.x + c.y + c.z;
  *(uint4*)&hist[base] = o;
  if (t == 255) blockSums[bid] = sums[255];
}

__global__ __launch_bounds__(256)
void scanB_k(unsigned* __restrict__ blockSums) {
  __shared__ unsigned sums[256];
  int t = threadIdx.x;
  unsigned s = blockSums[t];
  sums[t] = s;
  __syncthreads();
  for (int off = 1; off < 256; off <<= 1) {
    unsigned v = (t >= off) ? sums[t - off] : 0u;
    __syncthreads();
    sums[t] += v;
    __syncthreads();
  }
  blockSums[t] = sums[t] - s;
}

__global__ __launch_bounds__(256)
void scanC_k(unsigned* __restrict__ hist, const unsigned* __restrict__ blockSums) {
  int bid = blockIdx.x, t = threadIdx.x;
  unsigned off = blockSums[bid];
  unsigned base = (unsigned)bid * 1024u + (unsigned)t * 4u;
  uint4 c = *(uint4*)&hist[base];
  c.x += off; c.y += off; c.z += off; c.w += off;
  *(uint4*)&hist[base] = c;
}

__global__ __launch_bounds__(256)
void scatter_k(const float* __restrict__ dirs, unsigned* __restrict__ hist,
               float* __restrict__ sdirs, unsigned* __restrict__ order, int n) {
  int i = blockIdx.x * 256 + threadIdx.x;
  if (i >= n) return;
  float dx = dirs[i * 3 + 0], dy = dirs[i * 3 + 1], dz = dirs[i * 3 + 2];
  unsigned key = ray_key(dx, dy, dz);
  unsigned pos = atomicAdd(&hist[key], 1u);
  sdirs[pos * 3 + 0] = dx;
  sdirs[pos * 3 + 1] = dy;
  sdirs[pos * 3 + 2] = dz;
  order[pos] = i;
}

// ============ FUSED encode + MLP ============
// r10 lesson: encode (latency-bound, MfmaUtil 0) and MLP (overhead-bound,
// ~6% MFMA) ran serially, plus 256 MB of ws round-trip between them.
// Fusion: per block, 256 sorted rays; 8 sequential level-pair gathers
// (verified encode_k7 body) -> LDS feature tile F[16][257] (stride 257:
// conflict-free writes AND reads); one barrier; verified mlp_mfma4 body
// reading A-frags from F. Overlap comes from ~3 co-resident blocks/CU
// (53 KB LDS): one block's MFMA hides another's gather stalls (m114).
#define ROWS 72
#define FSTR 257   // F row stride in words (breaks 256-periodicity -> banks spread)

__global__ __launch_bounds__(256)
void fused_k(const float* __restrict__ sdirs,
             const float* __restrict__ table,
             const unsigned* __restrict__ order,
             const float* __restrict__ W1, const float* __restrict__ b1,
             const float* __restrict__ W2, const float* __restrict__ b2,
             const float* __restrict__ W3, const float* __restrict__ b3,
             float* __restrict__ out, int n, LevelParams lp)
{
  __shared__ unsigned F[NL * FSTR];     // 16.4 KB  [level][ray] packed bf16x2
  __shared__ short W1T[64 * ROWS];      // 9.2 KB
  __shared__ short W2T[64 * ROWS];      // 9.2 KB
  __shared__ short H1T[4][32 * ROWS];   // 18.4 KB

  int tid = threadIdx.x;

  // ---- stage weights (verified mlp_mfma4 staging; W1 rows permuted) ----
  {
    int nn = tid >> 2;
    int kg = tid & 3;
    bf16x8 v1a, v1b, v2a, v2b;
    #pragma unroll
    for (int j = 0; j < 8; ++j) {
      int k0 = kg * 16 + j, k1 = kg * 16 + 8 + j;
      v1a[j] = (k0 < 32) ? f2bf(W1[(k0 + 3) * 64 + nn])
             : (k0 < 35) ? f2bf(W1[(k0 - 32) * 64 + nn]) : (short)0;
      v1b[j] = (k1 < 32) ? f2bf(W1[(k1 + 3) * 64 + nn])
             : (k1 < 35) ? f2bf(W1[(k1 - 32) * 64 + nn]) : (short)0;
      v2a[j] = f2bf(W2[k0 * 64 + nn]);
      v2b[j] = f2bf(W2[k1 * 64 + nn]);
    }
    int wo = nn * ROWS + kg * 16;
    *(bf16x8*)&W1T[wo]     = v1a;
    *(bf16x8*)&W1T[wo + 8] = v1b;
    *(bf16x8*)&W2T[wo]     = v2a;
    *(bf16x8*)&W2T[wo + 8] = v2b;
  }

  // ---- gather phase: thread owns ray (chunk*256 + tid), loops 8 level-pairs ----
  int chunk = blockIdx.x;
  int ray = chunk * 256 + tid;
  int rcg = ray < n ? ray : (n - 1);

  float X0 = sdirs[rcg * 3 + 0] * 0.49f + 0.49f;
  float X1 = sdirs[rcg * 3 + 1] * 0.49f + 0.49f;
  float X2 = sdirs[rcg * 3 + 2] * 0.49f + 0.49f;

  for (int l0 = 0; l0 < 8; ++l0) {
    float wa0[2][3], wa1[2][3];
    bool dns[2];
    unsigned didx[2][8];
    unsigned par[2][4];
    const float2* tb[2];

    #pragma unroll
    for (int g = 0; g < 2; ++g) {
      int level = l0 + g * 8;
      float s = lp.scale[level];
      unsigned r = lp.res[level];
      dns[g] = (lp.dense_mask >> level) & 1u;

      float px = X0 * s + 0.5f, py = X1 * s + 0.5f, pz = X2 * s + 0.5f;
      float gx = floorf(px), gy = floorf(py), gz = floorf(pz);
      float fx = px - gx, fy = py - gy, fz = pz - gz;
      unsigned ix = (unsigned)gx, iy = (unsigned)gy, iz = (unsigned)gz;

      wa1[g][0] = fx * fx * (3.0f - 2.0f * fx);
      wa1[g][1] = fy * fy * (3.0f - 2.0f * fy);
      wa1[g][2] = fz * fz * (3.0f - 2.0f * fz);
      wa0[g][0] = 1.0f - wa1[g][0];
      wa0[g][1] = 1.0f - wa1[g][1];
      wa0[g][2] = 1.0f - wa1[g][2];

      if (dns[g]) {
        unsigned r2 = r * r;
        unsigned x0 = ix, x1 = ix + 1u;
        unsigned y0 = iy * r, y1 = y0 + r;
        unsigned z0 = iz * r2, z1 = z0 + r2;
        didx[g][0] = x0 + y0 + z0; didx[g][1] = x1 + y0 + z0;
        didx[g][2] = x0 + y1 + z0; didx[g][3] = x1 + y1 + z0;
        didx[g][4] = x0 + y0 + z1; didx[g][5] = x1 + y0 + z1;
        didx[g][6] = x0 + y1 + z1; didx[g][7] = x1 + y1 + z1;
      } else {
        unsigned y0 = iy * 2654435761u, y1 = y0 + 2654435761u;  // uint32 wrap == ref
        unsigned z0 = iz * 805459861u,  z1 = z0 + 805459861u;
        unsigned p0 = (ix ^ y0 ^ z0) & TMASK;
        unsigned p1 = (ix ^ y1 ^ z0) & TMASK;
        unsigned p2 = (ix ^ y0 ^ z1) & TMASK;
        unsigned p3 = (ix ^ y1 ^ z1) & TMASK;
        didx[g][0] = p0 >> 1; didx[g][1] = p1 >> 1;
        didx[g][2] = p2 >> 1; didx[g][3] = p3 >> 1;
        par[g][0] = p0 & 1u; par[g][1] = p1 & 1u;
        par[g][2] = p2 & 1u; par[g][3] = p3 & 1u;
      }
      tb[g] = (const float2*)table + (size_t)level * TSIZE;
    }

    float2 v[2][8];
    float4 f4[2][4];
    #pragma unroll
    for (int g = 0; g < 2; ++g) {
      if (dns[g]) {
        #pragma unroll
        for (int c = 0; c < 8; ++c) v[g][c] = tb[g][didx[g][c]];
      } else {
        const float4* t4p = (const float4*)tb[g];
        #pragma unroll
        for (int c = 0; c < 4; ++c) f4[g][c] = t4p[didx[g][c]];
      }
    }
    #pragma unroll
    for (int g = 0; g < 2; ++g) {
      if (!dns[g]) {
        #pragma unroll
        for (int c = 0; c < 4; ++c) {
          float2 even, odd;
          even.x = f4[g][c].x; even.y = f4[g][c].y;
          odd.x  = f4[g][c].z; odd.y  = f4[g][c].w;
          bool o = par[g][c] != 0;
          v[g][2 * c]     = o ? odd : even;
          v[g][2 * c + 1] = o ? even : odd;
        }
      }
    }

    #pragma unroll
    for (int g = 0; g < 2; ++g) {
      float wx0 = wa0[g][0], wx1 = wa1[g][0];
      float wy0 = wa0[g][1], wy1 = wa1[g][1];
      float wz0 = wa0[g][2], wz1 = wa1[g][2];
      float wy0z0 = wy0 * wz0, wy1z0 = wy1 * wz0, wy0z1 = wy0 * wz1, wy1z1 = wy1 * wz1;
      float w000 = wx0 * wy0z0, w100 = wx1 * wy0z0;
      float w010 = wx0 * wy1z0, w110 = wx1 * wy1z0;
      float w001 = wx0 * wy0z1, w101 = wx1 * wy0z1;
      float w011 = wx0 * wy1z1, w111 = wx1 * wy1z1;

      float a0 = w000 * v[g][0].x + w100 * v[g][1].x + w010 * v[g][2].x + w110 * v[g][3].x
               + w001 * v[g][4].x + w101 * v[g][5].x + w011 * v[g][6].x + w111 * v[g][7].x;
      float a1 = w000 * v[g][0].y + w100 * v[g][1].y + w010 * v[g][2].y + w110 * v[g][3].y
               + w001 * v[g][4].y + w101 * v[g][5].y + w011 * v[g][6].y + w111 * v[g][7].y;

      int level = l0 + g * 8;
      unsigned packed = ((unsigned)f2bf(a0) & 0xffffu) | (((unsigned)f2bf(a1) & 0xffffu) << 16);
      F[level * FSTR + tid] = packed;
    }
  }
  __syncthreads();   // F + weights visible to all lanes (round-3 lesson)

  // ---- MLP phase (verified mlp_mfma4 body; A-frags from LDS F) ----
  int wave = tid >> 6, lane = tid & 63;
  int q = lane >> 4, nl = lane & 15;

  float b1v[4], b2v[4], w3v[4];
  #pragma unroll
  for (int t4 = 0; t4 < 4; ++t4) {
    b1v[t4] = b1[t4 * 16 + nl];
    b2v[t4] = b2[t4 * 16 + nl];
    w3v[t4] = W3[t4 * 16 + nl];
  }
  float b3s = b3[0];

  for (int batch = 0; batch < 2; ++batch) {   // wave: 2 batches x 32 rays
    int lbase = wave * 64 + batch * 32;       // local ray base within block

    bf16x8 a0[2], a1[2];
    #pragma unroll
    for (int t = 0; t < 2; ++t) {
      int rl = lbase + t * 16 + nl;           // local ray 0..255
      unsigned u0 = F[(q * 4 + 0) * FSTR + rl];
      unsigned u1 = F[(q * 4 + 1) * FSTR + rl];
      unsigned u2 = F[(q * 4 + 2) * FSTR + rl];
      unsigned u3 = F[(q * 4 + 3) * FSTR + rl];
      a0[t][0] = lo16(u0); a0[t][1] = hi16(u0); a0[t][2] = lo16(u1); a0[t][3] = hi16(u1);
      a0[t][4] = lo16(u2); a0[t][5] = hi16(u2); a0[t][6] = lo16(u3); a0[t][7] = hi16(u3);
      a1[t][0] = 0; a1[t][1] = 0; a1[t][2] = 0; a1[t][3] = 0;
      a1[t][4] = 0; a1[t][5] = 0; a1[t][6] = 0; a1[t][7] = 0;
      if (q == 0) {                           // k'=32..34 are the dirs
        int rg = chunk * 256 + rl;
        int rc = rg < n ? rg : (n - 1);
        a1[t][0] = f2bf(sdirs[rc * 3 + 0]);
        a1[t][1] = f2bf(sdirs[rc * 3 + 1]);
        a1[t][2] = f2bf(sdirs[rc * 3 + 2]);
      }
    }

    f32x4 acc[2][4];
    #pragma unroll
    for (int t4 = 0; t4 < 4; ++t4) {
      int brow = (t4 * 16 + nl) * ROWS;
      bf16x8 bt0 = *(const bf16x8*)&W1T[brow + q * 8];
      bf16x8 bt1 = *(const bf16x8*)&W1T[brow + 32 + q * 8];
      #pragma unroll
      for (int t = 0; t < 2; ++t) {
        f32x4 z = {0.f, 0.f, 0.f, 0.f};
        z = __builtin_amdgcn_mfma_f32_16x16x32_bf16(a0[t], bt0, z, 0, 0, 0);
        z = __builtin_amdgcn_mfma_f32_16x16x32_bf16(a1[t], bt1, z, 0, 0, 0);
        acc[t][t4] = z;
      }
    }
    #pragma unroll
    for (int t = 0; t < 2; ++t)
      #pragma unroll
      for (int t4 = 0; t4 < 4; ++t4)
        #pragma unroll
        for (int i = 0; i < 4; ++i) {
          float v = fmaxf(acc[t][t4][i] + b1v[t4], 0.0f);
          H1T[wave][(t * 16 + q * 4 + i) * ROWS + t4 * 16 + nl] = f2bf(v);
        }
    __syncthreads();   // H1 visible + compiler fence

    #pragma unroll
    for (int t4 = 0; t4 < 4; ++t4) {
      int brow = (t4 * 16 + nl) * ROWS;
      bf16x8 bt0 = *(const bf16x8*)&W2T[brow + q * 8];
      bf16x8 bt1 = *(const bf16x8*)&W2T[brow + 32 + q * 8];
      #pragma unroll
      for (int t = 0; t < 2; ++t) {
        bf16x8 h0 = *(const bf16x8*)&H1T[wave][(t * 16 + nl) * ROWS + q * 8];
        bf16x8 h1f = *(const bf16x8*)&H1T[wave][(t * 16 + nl) * ROWS + 32 + q * 8];
        f32x4 z = {0.f, 0.f, 0.f, 0.f};
        z = __builtin_amdgcn_mfma_f32_16x16x32_bf16(h0, bt0, z, 0, 0, 0);
        z = __builtin_amdgcn_mfma_f32_16x16x32_bf16(h1f, bt1, z, 0, 0, 0);
        acc[t][t4] = z;
      }
    }

    #pragma unroll
    for (int t = 0; t < 2; ++t) {
      float part[4] = {0.f, 0.f, 0.f, 0.f};
      #pragma unroll
      for (int t4 = 0; t4 < 4; ++t4)
        #pragma unroll
        for (int i = 0; i < 4; ++i) {
          float v = fmaxf(acc[t][t4][i] + b2v[t4], 0.0f);
          part[i] = fmaf(v, w3v[t4], part[i]);
        }
      #pragma unroll
      for (int s = 1; s < 16; s <<= 1) {
        #pragma unroll
        for (int i = 0; i < 4; ++i) part[i] += __shfl_xor(part[i], s, 64);
      }
      if (nl == 0) {
        int orow = chunk * 256 + lbase + t * 16 + q * 4;
        #pragma unroll
        for (int i = 0; i < 4; ++i) {
          if (orow + i < n) {
            float v = part[i] + b3s + 1.0f;
            out[order[orow + i]] = fmaxf(v, 0.0f) + log1pf(expf(-fabsf(v)));
          }
        }
      }
    }
    __syncthreads();   // WAR: next batch's H1T write must not pass reads
  }
}

// ============ Fallback A (ws >= 128 MiB, unsorted): r9-verified split =======
__global__ __launch_bounds__(256)
void encode_k7(const float* __restrict__ dirs,
               const float* __restrict__ table,
               unsigned* __restrict__ ws,
               int n, LevelParams lp)
{
  int b = blockIdx.x;
  int l0 = (b >> 3) & 7;
  int chunk = ((b >> 6) << 3) + (b & 7);
  int ray = chunk * 256 + threadIdx.x;
  if (ray >= n) return;

  float X0 = dirs[ray * 3 + 0] * 0.49f + 0.49f;
  float X1 = dirs[ray * 3 + 1] * 0.49f + 0.49f;
  float X2 = dirs[ray * 3 + 2] * 0.49f + 0.49f;

  float wa0[2][3], wa1[2][3];
  bool dns[2];
  unsigned didx[2][8];
  unsigned par[2][4];
  const float2* tb[2];

  #pragma unroll
  for (int g = 0; g < 2; ++g) {
    int level = l0 + g * 8;
    float s = lp.scale[level];
    unsigned r = lp.res[level];
    dns[g] = (lp.dense_mask >> level) & 1u;

    float px = X0 * s + 0.5f, py = X1 * s + 0.5f, pz = X2 * s + 0.5f;
    float gx = floorf(px), gy = floorf(py), gz = floorf(pz);
    float fx = px - gx, fy = py - gy, fz = pz - gz;
    unsigned ix = (unsigned)gx, iy = (unsigned)gy, iz = (unsigned)gz;

    wa1[g][0] = fx * fx * (3.0f - 2.0f * fx);
    wa1[g][1] = fy * fy * (3.0f - 2.0f * fy);
    wa1[g][2] = fz * fz * (3.0f - 2.0f * fz);
    wa0[g][0] = 1.0f - wa1[g][0];
    wa0[g][1] = 1.0f - wa1[g][1];
    wa0[g][2] = 1.0f - wa1[g][2];

    if (dns[g]) {
      unsigned r2 = r * r;
      unsigned x0 = ix, x1 = ix + 1u;
      unsigned y0 = iy * r, y1 = y0 + r;
      unsigned z0 = iz * r2, z1 = z0 + r2;
      didx[g][0] = x0 + y0 + z0; didx[g][1] = x1 + y0 + z0;
      didx[g][2] = x0 + y1 + z0; didx[g][3] = x1 + y1 + z0;
      didx[g][4] = x0 + y0 + z1; didx[g][5] = x1 + y0 + z1;
      didx[g][6] = x0 + y1 + z1; didx[g][7] = x1 + y1 + z1;
    } else {
      unsigned y0 = iy * 2654435761u, y1 = y0 + 2654435761u;
      unsigned z0 = iz * 805459861u,  z1 = z0 + 805459861u;
      unsigned p0 = (ix ^ y0 ^ z0) & TMASK;
      unsigned p1 = (ix ^ y1 ^ z0) & TMASK;
      unsigned p2 = (ix ^ y0 ^ z1) & TMASK;
      unsigned p3 = (ix ^ y1 ^ z1) & TMASK;
      didx[g][0] = p0 >> 1; didx[g][1] = p1 >> 1;
      didx[g][2] = p2 >> 1; didx[g][3] = p3 >> 1;
      par[g][0] = p0 & 1u; par[g][1] = p1 & 1u;
      par[g][2] = p2 & 1u; par[g][3] = p3 & 1u;
    }
    tb[g] = (const float2*)table + (size_t)level * TSIZE;
  }

  float2 v[2][8];
  float4 f4[2][4];
  #pragma unroll
  for (int g = 0; g < 2; ++g) {
    if (dns[g]) {
      #pragma unroll
      for (int c = 0; c < 8; ++c) v[g][c] = tb[g][didx[g][c]];
    } else {
      const float4* t4p = (const float4*)tb[g];
      #pragma unroll
      for (int c = 0; c < 4; ++c) f4[g][c] = t4p[didx[g][c]];
    }
  }
  #pragma unroll
  for (int g = 0; g < 2; ++g) {
    if (!dns[g]) {
      #pragma unroll
      for (int c = 0; c < 4; ++c) {
        float2 even, odd;
        even.x = f4[g][c].x; even.y = f4[g][c].y;
        odd.x  = f4[g][c].z; odd.y  = f4[g][c].w;
        bool o = par[g][c] != 0;
        v[g][2 * c]     = o ? odd : even;
        v[g][2 * c + 1] = o ? even : odd;
      }
    }
  }

  #pragma unroll
  for (int g = 0; g < 2; ++g) {
    float wx0 = wa0[g][0], wx1 = wa1[g][0];
    float wy0 = wa0[g][1], wy1 = wa1[g][1];
    float wz0 = wa0[g][2], wz1 = wa1[g][2];
    float wy0z0 = wy0 * wz0, wy1z0 = wy1 * wz0, wy0z1 = wy0 * wz1, wy1z1 = wy1 * wz1;
    float w000 = wx0 * wy0z0, w100 = wx1 * wy0z0;
    float w010 = wx0 * wy1z0, w110 = wx1 * wy1z0;
    float w001 = wx0 * wy0z1, w101 = wx1 * wy0z1;
    float w011 = wx0 * wy1z1, w111 = wx1 * wy1z1;

    float a0 = w000 * v[g][0].x + w100 * v[g][1].x + w010 * v[g][2].x + w110 * v[g][3].x
             + w001 * v[g][4].x + w101 * v[g][5].x + w011 * v[g][6].x + w111 * v[g][7].x;
    float a1 = w000 * v[g][0].y + w100 * v[g][1].y + w010 * v[g][2].y + w110 * v[g][3].y
             + w001 * v[g][4].y + w101 * v[g][5].y + w011 * v[g][6].y + w111 * v[g][7].y;

    int level = l0 + g * 8;
    unsigned packed = ((unsigned)f2bf(a0) & 0xffffu) | (((unsigned)f2bf(a1) & 0xffffu) << 16);
    ws[(size_t)level * n + ray] = packed;
  }
}

#define RPB 512
__global__ __launch_bounds__(256)
void mlp_mfma3(const float* __restrict__ dirs,
               const unsigned* __restrict__ ws,
               const float* __restrict__ W1, const float* __restrict__ b1,
               const float* __restrict__ W2, const float* __restrict__ b2,
               const float* __restrict__ W3, const float* __restrict__ b3,
               float* __restrict__ out, int n)
{
  __shared__ short W1T[64 * ROWS];
  __shared__ short W2T[64 * ROWS];
  __shared__ short H1T[4][32 * ROWS];

  int tid = threadIdx.x;
  {
    int nn = tid >> 2;
    int kg = tid & 3;
    bf16x8 v1a, v1b, v2a, v2b;
    #pragma unroll
    for (int j = 0; j < 8; ++j) {
      int k0 = kg * 16 + j, k1 = kg * 16 + 8 + j;
      v1a[j] = (k0 < 32) ? f2bf(W1[(k0 + 3) * 64 + nn])
             : (k0 < 35) ? f2bf(W1[(k0 - 32) * 64 + nn]) : (short)0;
      v1b[j] = (k1 < 32) ? f2bf(W1[(k1 + 3) * 64 + nn])
             : (k1 < 35) ? f2bf(W1[(k1 - 32) * 64 + nn]) : (short)0;
      v2a[j] = f2bf(W2[k0 * 64 + nn]);
      v2b[j] = f2bf(W2[k1 * 64 + nn]);
    }
    int wo = nn * ROWS + kg * 16;
    *(bf16x8*)&W1T[wo]     = v1a;
    *(bf16x8*)&W1T[wo + 8] = v1b;
    *(bf16x8*)&W2T[wo]     = v2a;
    *(bf16x8*)&W2T[wo + 8] = v2b;
  }
  __syncthreads();

  int wave = tid >> 6, lane = tid & 63;
  int q = lane >> 4, nl = lane & 15;

  float b1v[4], b2v[4], w3v[4];
  #pragma unroll
  for (int t4 = 0; t4 < 4; ++t4) {
    b1v[t4] = b1[t4 * 16 + nl];
    b2v[t4] = b2[t4 * 16 + nl];
    w3v[t4] = W3[t4 * 16 + nl];
  }
  float b3s = b3[0];

  int blockBase = blockIdx.x * RPB;

  for (int batch = 0; batch < RPB / 128; ++batch) {
    int wbase = blockBase + batch * 128 + wave * 32;
    bf16x8 a0[2], a1[2];
    #pragma unroll
    for (int t = 0; t < 2; ++t) {
      int rr = wbase + t * 16 + nl;
      int rc = rr < n ? rr : (n - 1);
      unsigned u0 = ws[(size_t)(q * 4 + 0) * n + rc];
      unsigned u1 = ws[(size_t)(q * 4 + 1) * n + rc];
      unsigned u2 = ws[(size_t)(q * 4 + 2) * n + rc];
      unsigned u3 = ws[(size_t)(q * 4 + 3) * n + rc];
      a0[t][0] = lo16(u0); a0[t][1] = hi16(u0); a0[t][2] = lo16(u1); a0[t][3] = hi16(u1);
      a0[t][4] = lo16(u2); a0[t][5] = hi16(u2); a0[t][6] = lo16(u3); a0[t][7] = hi16(u3);
      a1[t][0] = 0; a1[t][1] = 0; a1[t][2] = 0; a1[t][3] = 0;
      a1[t][4] = 0; a1[t][5] = 0; a1[t][6] = 0; a1[t][7] = 0;
      if (q == 0) {
        a1[t][0] = f2bf(dirs[rc * 3 + 0]);
        a1[t][1] = f2bf(dirs[rc * 3 + 1]);
        a1[t][2] = f2bf(dirs[rc * 3 + 2]);
      }
    }

    f32x4 acc[2][4];
    #pragma unroll
    for (int t4 = 0; t4 < 4; ++t4) {
      int brow = (t4 * 16 + nl) * ROWS;
      bf16x8 bt0 = *(const bf16x8*)&W1T[brow + q * 8];
      bf16x8 bt1 = *(const bf16x8*)&W1T[brow + 32 + q * 8];
      #pragma unroll
      for (int t = 0; t < 2; ++t) {
        f32x4 z = {0.f, 0.f, 0.f, 0.f};
        z = __builtin_amdgcn_mfma_f32_16x16x32_bf16(a0[t], bt0, z, 0, 0, 0);
        z = __builtin_amdgcn_mfma_f32_16x16x32_bf16(a1[t], bt1, z, 0, 0, 0);
        acc[t][t4] = z;
      }
    }
    #pragma unroll
    for (int t = 0; t < 2; ++t)
      #pragma unroll
      for (int t4 = 0; t4 < 4; ++t4)
        #pragma unroll
        for (int i = 0; i < 4; ++i) {
          float v = fmaxf(acc[t][t4][i] + b1v[t4], 0.0f);
          H1T[wave][(t * 16 + q * 4 + i) * ROWS + t4 * 16 + nl] = f2bf(v);
        }
    __syncthreads();

    #pragma unroll
    for (int t4 = 0; t4 < 4; ++t4) {
      int brow = (t4 * 16 + nl) * ROWS;
      bf16x8 bt0 = *(const bf16x8*)&W2T[brow + q * 8];
      bf16x8 bt1 = *(const bf16x8*)&W2T[brow + 32 + q * 8];
      #pragma unroll
      for (int t = 0; t < 2; ++t) {
        bf16x8 h0 = *(const bf16x8*)&H1T[wave][(t * 16 + nl) * ROWS + q * 8];
        bf16x8 h1f = *(const bf16x8*)&H1T[wave][(t * 16 + nl) * ROWS + 32 + q * 8];
        f32x4 z = {0.f, 0.f, 0.f, 0.f};
        z = __builtin_amdgcn_mfma_f32_16x16x32_bf16(h0, bt0, z, 0, 0, 0);
        z = __builtin_amdgcn_mfma_f32_16x16x32_bf16(h1f, bt1, z, 0, 0, 0);
        acc[t][t4] = z;
      }
    }

    #pragma unroll
    for (int t = 0; t < 2; ++t) {
      float part[4] = {0.f, 0.f, 0.f, 0.f};
      #pragma unroll
      for (int t4 = 0; t4 < 4; ++t4)
        #pragma unroll
        for (int i = 0; i < 4; ++i) {
          float v = fmaxf(acc[t][t4][i] + b2v[t4], 0.0f);
          part[i] = fmaf(v, w3v[t4], part[i]);
        }
      #pragma unroll
      for (int s = 1; s < 16; s <<= 1) {
        #pragma unroll
        for (int i = 0; i < 4; ++i) part[i] += __shfl_xor(part[i], s, 64);
      }
      if (nl == 0) {
        int orow = wbase + t * 16 + q * 4;
        float ov[4];
        #pragma unroll
        for (int i = 0; i < 4; ++i) {
          float v = part[i] + b3s + 1.0f;
          ov[i] = fmaxf(v, 0.0f) + log1pf(expf(-fabsf(v)));
        }
        if (orow + 3 < n) {
          float4 o4; o4.x = ov[0]; o4.y = ov[1]; o4.z = ov[2]; o4.w = ov[3];
          *(float4*)&out[orow] = o4;
        } else {
          for (int i = 0; i < 4; ++i) if (orow + i < n) out[orow + i] = ov[i];
        }
      }
    }
    __syncthreads();
  }
}

// ============ Fallback B: round-1 fused scalar kernel (tiny ws) =============
__global__ __launch_bounds__(256)
void sdf_fused(const float* __restrict__ dirs,
               const float* __restrict__ table,
               const float* __restrict__ W1, const float* __restrict__ b1,
               const float* __restrict__ W2, const float* __restrict__ b2,
               const float* __restrict__ W3, const float* __restrict__ b3,
               float* __restrict__ out, int n, LevelParams lp)
{
  int gid = blockIdx.x * 256 + threadIdx.x;
  if (gid >= n) return;
  float dx = dirs[gid * 3 + 0], dy = dirs[gid * 3 + 1], dz = dirs[gid * 3 + 2];
  float xx = dx * 0.49f + 0.49f, xy = dy * 0.49f + 0.49f, xz = dz * 0.49f + 0.49f;
  float h[35];
  h[0] = dx; h[1] = dy; h[2] = dz;
  #pragma unroll
  for (int l = 0; l < NL; ++l) {
    float s = lp.scale[l];
    float px = xx * s + 0.5f, py = xy * s + 0.5f, pz = xz * s + 0.5f;
    float gx = floorf(px), gy = floorf(py), gz = floorf(pz);
    float fx = px - gx, fy = py - gy, fz = pz - gz;
    unsigned ix = (unsigned)gx, iy = (unsigned)gy, iz = (unsigned)gz;
    float wx1 = fx * fx * (3.0f - 2.0f * fx);
    float wy1 = fy * fy * (3.0f - 2.0f * fy);
    float wz1 = fz * fz * (3.0f - 2.0f * fz);
    float wx0 = 1.0f - wx1, wy0 = 1.0f - wy1, wz0 = 1.0f - wz1;
    unsigned i000, i100, i010, i110, i001, i101, i011, i111;
    if ((lp.dense_mask >> l) & 1u) {
      unsigned r = lp.res[l], r2 = r * r;
      unsigned x0 = ix, x1 = ix + 1u, y0 = iy * r, y1 = y0 + r, z0 = iz * r2, z1 = z0 + r2;
      i000 = x0 + y0 + z0; i100 = x1 + y0 + z0; i010 = x0 + y1 + z0; i110 = x1 + y1 + z0;
      i001 = x0 + y0 + z1; i101 = x1 + y0 + z1; i011 = x0 + y1 + z1; i111 = x1 + y1 + z1;
    } else {
      unsigned x0 = ix, x1 = ix + 1u;
      unsigned y0 = iy * 2654435761u, y1 = y0 + 2654435761u;
      unsigned z0 = iz * 805459861u,  z1 = z0 + 805459861u;
      i000 = (x0 ^ y0 ^ z0) & TMASK; i100 = (x1 ^ y0 ^ z0) & TMASK;
      i010 = (x0 ^ y1 ^ z0) & TMASK; i110 = (x1 ^ y1 ^ z0) & TMASK;
      i001 = (x0 ^ y0 ^ z1) & TMASK; i101 = (x1 ^ y0 ^ z1) & TMASK;
      i011 = (x0 ^ y1 ^ z1) & TMASK; i111 = (x1 ^ y1 ^ z1) & TMASK;
    }
    const float2* t = (const float2*)table + (size_t)l * TSIZE;
    float2 f000 = t[i000], f100 = t[i100], f010 = t[i010], f110 = t[i110];
    float2 f001 = t[i001], f101 = t[i101], f011 = t[i011], f111 = t[i111];
    float wy0z0 = wy0 * wz0, wy1z0 = wy1 * wz0, wy0z1 = wy0 * wz1, wy1z1 = wy1 * wz1;
    float w000 = wx0 * wy0z0, w100 = wx1 * wy0z0, w010 = wx0 * wy1z0, w110 = wx1 * wy1z0;
    float w001 = wx0 * wy0z1, w101 = wx1 * wy0z1, w011 = wx0 * wy1z1, w111 = wx1 * wy1z1;
    h[3 + 2 * l] = w000 * f000.x + w100 * f100.x + w010 * f010.x + w110 * f110.x
                 + w001 * f001.x + w101 * f101.x + w011 * f011.x + w111 * f111.x;
    h[4 + 2 * l] = w000 * f000.y + w100 * f100.y + w010 * f010.y + w110 * f110.y
                 + w001 * f001.y + w101 * f101.y + w011 * f011.y + w111 * f111.y;
  }
  float h1[64];
  #pragma unroll
  for (int j = 0; j < 64; ++j) {
    float acc = b1[j];
    #pragma unroll
    for (int i = 0; i < 35; ++i) acc = fmaf(h[i], W1[i * 64 + j], acc);
    h1[j] = fmaxf(acc, 0.0f);
  }
  float h2[64];
  #pragma unroll
  for (int j = 0; j < 64; ++j) {
    float acc = b2[j];
    #pragma unroll
    for (int i = 0; i < 64; ++i) acc = fmaf(h1[i], W2[i * 64 + j], acc);
    h2[j] = fmaxf(acc, 0.0f);
  }
  float o = b3[0];
  #pragma unroll
  for (int i = 0; i < 64; ++i) o = fmaf(h2[i], W3[i], o);
  float v = o + 1.0f;
  out[gid] = fmaxf(v, 0.0f) + log1pf(expf(-fabsf(v)));
}

extern "C" void kernel_launch(void* const* d_in, const int* in_sizes, int n_in,
                              void* d_out, int out_size, void* d_ws, size_t ws_size,
                              hipStream_t stream) {
  const float* dirs  = (const float*)d_in[0];
  const float* table = (const float*)d_in[1];
  const float* W1 = (const float*)d_in[2];
  const float* b1 = (const float*)d_in[3];
  const float* W2 = (const float*)d_in[4];
  const float* b2 = (const float*)d_in[5];
  const float* W3 = (const float*)d_in[6];
  const float* b3 = (const float*)d_in[7];
  float* out = (float*)d_out;
  int n = in_sizes[0] / 3;

  LevelParams lp;
  double pls = std::exp(std::log(2048.0 / 16.0) / 15.0);
  unsigned dm = 0;
  for (int l = 0; l < NL; ++l) {
    double scale = 16.0 * std::pow(pls, (double)l) - 1.0;
    lp.scale[l] = (float)scale;
    long long res = (long long)std::ceil(scale) + 1;
    lp.res[l] = (unsigned)res;
    if (res * res * res <= (long long)TSIZE) dm |= (1u << l);
  }
  lp.dense_mask = dm;

  size_t sdirs_bytes = (size_t)n * 12;
  size_t order_bytes = (size_t)n * 4;
  size_t hist_bytes  = (size_t)NBINS * 4;
  size_t bsum_bytes  = 256 * 4;
  size_t sorted_need = sdirs_bytes + order_bytes + hist_bytes + bsum_bytes;  // ~33 MiB
  size_t feat_bytes  = (size_t)n * NL * 4;    // for unsorted fallback

  int blocks256 = (n + 255) / 256;

  if (ws_size >= sorted_need) {
    char* base = (char*)d_ws;
    float*    sdirs = (float*)base;
    unsigned* order = (unsigned*)(base + sdirs_bytes);
    unsigned* hist  = (unsigned*)(base + sdirs_bytes + order_bytes);
    unsigned* bsums = (unsigned*)(base + sdirs_bytes + order_bytes + hist_bytes);

    hipMemsetAsync(hist, 0, hist_bytes, stream);
    hipLaunchKernelGGL(hist_k, dim3(blocks256), dim3(256), 0, stream, dirs, hist, n);
    hipLaunchKernelGGL(scanA_k, dim3(256), dim3(256), 0, stream, hist, bsums);
    hipLaunchKernelGGL(scanB_k, dim3(1), dim3(256), 0, stream, bsums);
    hipLaunchKernelGGL(scanC_k, dim3(256), dim3(256), 0, stream, hist, bsums);
    hipLaunchKernelGGL(scatter_k, dim3(blocks256), dim3(256), 0, stream,
                       dirs, hist, sdirs, order, n);
    hipLaunchKernelGGL(fused_k, dim3(blocks256), dim3(256), 0, stream,
                       sdirs, table, order, W1, b1, W2, b2, W3, b3, out, n, lp);
  } else if (ws_size >= feat_bytes) {
    unsigned* feats = (unsigned*)d_ws;
    int chunks8 = ((blocks256 + 7) / 8) * 8;
    int enc_grid = 8 * chunks8;
    int mlp_blocks = (n + RPB - 1) / RPB;
    hipLaunchKernelGGL(encode_k7, dim3(enc_grid), dim3(256), 0, stream,
                       dirs, table, feats, n, lp);
    hipLaunchKernelGGL(mlp_mfma3, dim3(mlp_blocks), dim3(256), 0, stream,
                       dirs, feats, W1, b1, W2, b2, W3, b3, out, n);
  } else {
    hipLaunchKernelGGL(sdf_fused, dim3(blocks256), dim3(256), 0, stream,
                       dirs, table, W1, b1, W2, b2, W3, b3, out, n, lp);
  }
}